// Round 2
// baseline (9777.513 us; speedup 1.0000x reference)
//
#include <hip/hip_runtime.h>
#include <cstdint>

// ============================================================================
// ViT forward, MI355X round 1: correctness-first, bf16-MFMA GEMMs.
//
// Pipeline per call:
//   convT(patch_w) ; im2col(img)->bf16 ; GEMM[EPI_PATCH] -> x(+patch_b+pos)
//   cls row init
//   12x: LN1->bf16 ; convT(qkv_w); GEMM->qkv(bf16); flash-attn(f32)->o(bf16);
//        convT(out_w); GEMM[bias+res]->x ; LN2->bf16 ; convT(ff1_w);
//        GEMM[bias+GELU]->mlp(bf16) ; convT(ff2_w); GEMM[bias+res]->x
//   head: LN(cls) @ head_w + head_b -> d_out (f32)
//
// GEMM: 128x128 tile, BK=64, 4 waves (2x2 of 64x64), mfma_f32_16x16x32_bf16,
// reg-staged LDS, +8 bf16 row pad (144B rows, 16B aligned, ~2-way banks).
// Weights pre-transposed to bf16 (N x K) so B-fragment reads are ds_read_b128.
// ============================================================================

typedef __attribute__((ext_vector_type(8))) short bf16x8;
typedef __attribute__((ext_vector_type(4))) float f32x4;

#define NTOK 577

__device__ __forceinline__ ushort f2bf(float f) {
  union { float f; unsigned int u; } x; x.f = f;
  unsigned int r = x.u + 0x7fffu + ((x.u >> 16) & 1u);  // RNE
  return (ushort)(r >> 16);
}
__device__ __forceinline__ float bf2f(ushort u) {
  union { unsigned int u; float f; } x; x.u = ((unsigned int)u) << 16;
  return x.f;
}
__device__ __forceinline__ void bf8tof(int4 v, float* o) {
  const ushort* s = reinterpret_cast<const ushort*>(&v);
#pragma unroll
  for (int i = 0; i < 8; ++i) o[i] = bf2f(s[i]);
}

// ---------------------------------------------------------------------------
// f32 W[K][N]  ->  bf16 Wt[N][K]   (tiled transpose, coalesced both sides)
// ---------------------------------------------------------------------------
__global__ __launch_bounds__(256) void convt_kernel(const float* __restrict__ W,
                                                    ushort* __restrict__ Wt,
                                                    int K, int N) {
  __shared__ float t[32][33];
  const int kb = blockIdx.x * 32, nb = blockIdx.y * 32;
  const int tx = threadIdx.x & 31, ty = threadIdx.x >> 5;
#pragma unroll
  for (int i = 0; i < 32; i += 8)
    t[ty + i][tx] = W[(size_t)(kb + ty + i) * N + (nb + tx)];
  __syncthreads();
#pragma unroll
  for (int i = 0; i < 32; i += 8)
    Wt[(size_t)(nb + ty + i) * K + (kb + tx)] = f2bf(t[tx][ty + i]);
}

// ---------------------------------------------------------------------------
// im2col: img (B,3,384,384) f32 -> Apatch (9216 x 768) bf16
// patch-dim index j = (py*16+px)*3 + c ; row m = b*576 + gy*24 + gx
// ---------------------------------------------------------------------------
__global__ __launch_bounds__(256) void im2col_kernel(const float* __restrict__ img,
                                                     ushort* __restrict__ Ap) {
  const int idx = blockIdx.x * 256 + threadIdx.x;  // 9216*768 exactly
  const int j = idx % 768;
  const int m = idx / 768;
  const int c = j % 3;
  const int q = j / 3;
  const int px = q & 15, py = q >> 4;
  const int b = m / 576, p = m % 576;
  const int gy = p / 24, gx = p % 24;
  const float v = img[((size_t)(b * 3 + c) * 384 + (gy * 16 + py)) * 384 + (gx * 16 + px)];
  Ap[idx] = f2bf(v);
}

__global__ void clspos_kernel(const float* __restrict__ cls_tok,
                              const float* __restrict__ pos,
                              float* __restrict__ x) {
  const int i = blockIdx.x * 256 + threadIdx.x;  // 16*768
  const int b = i / 768, d = i % 768;
  x[(size_t)b * NTOK * 768 + d] = cls_tok[d] + pos[d];
}

// ---------------------------------------------------------------------------
// LayerNorm row kernel: x f32 row (768) -> bf16 out row. 1 wave per row.
// ---------------------------------------------------------------------------
__global__ __launch_bounds__(64) void ln_kernel(const float* __restrict__ x,
                                                const float* __restrict__ w,
                                                const float* __restrict__ bb,
                                                ushort* __restrict__ out) {
  const int row = blockIdx.x, lane = threadIdx.x;
  const float4* xr = reinterpret_cast<const float4*>(x + (size_t)row * 768);
  const float4 v0 = xr[lane], v1 = xr[lane + 64], v2 = xr[lane + 128];
  float vals[12] = {v0.x, v0.y, v0.z, v0.w, v1.x, v1.y, v1.z, v1.w,
                    v2.x, v2.y, v2.z, v2.w};
  float s = 0.f;
#pragma unroll
  for (int i = 0; i < 12; ++i) s += vals[i];
#pragma unroll
  for (int o = 32; o; o >>= 1) s += __shfl_xor(s, o);
  const float mu = s * (1.0f / 768.0f);
  float q = 0.f;
#pragma unroll
  for (int i = 0; i < 12; ++i) { const float d = vals[i] - mu; q += d * d; }
#pragma unroll
  for (int o = 32; o; o >>= 1) q += __shfl_xor(q, o);
  const float rstd = rsqrtf(q * (1.0f / 768.0f) + 1e-5f);
  const float4* w4 = reinterpret_cast<const float4*>(w);
  const float4* b4 = reinterpret_cast<const float4*>(bb);
  ushort* orow = out + (size_t)row * 768;
#pragma unroll
  for (int ch = 0; ch < 3; ++ch) {
    const float4 wv = w4[lane + ch * 64];
    const float4 bv = b4[lane + ch * 64];
    ushort4 u;
    u.x = f2bf((vals[ch * 4 + 0] - mu) * rstd * wv.x + bv.x);
    u.y = f2bf((vals[ch * 4 + 1] - mu) * rstd * wv.y + bv.y);
    u.z = f2bf((vals[ch * 4 + 2] - mu) * rstd * wv.z + bv.z);
    u.w = f2bf((vals[ch * 4 + 3] - mu) * rstd * wv.w + bv.w);
    *reinterpret_cast<ushort4*>(orow + ch * 256 + lane * 4) = u;
  }
}

// ---------------------------------------------------------------------------
// MFMA GEMM: C(MxN) = A(MxK bf16) @ W  with W given transposed Bt(NxK bf16).
// ---------------------------------------------------------------------------
constexpr int EPI_BF16 = 0;       // C = acc                     -> bf16
constexpr int EPI_GELU_BF16 = 1;  // C = gelu(acc + bias)        -> bf16
constexpr int EPI_RES_F32 = 2;    // C = acc + bias + extra[r,c] -> f32
constexpr int EPI_PATCH = 3;      // x[row+b+1] = acc + patch_b + pos[p+1]

template <int EPI>
__global__ __launch_bounds__(256) void gemm_kernel(
    const ushort* __restrict__ A, const ushort* __restrict__ Bt,
    const float* __restrict__ bias, const float* __restrict__ extra,
    void* __restrict__ Cptr, int M, int N, int K) {
  __shared__ ushort Alds[128][72];
  __shared__ ushort Blds[128][72];
  const int tid = threadIdx.x;
  const int tileM = blockIdx.x * 128, tileN = blockIdx.y * 128;
  const int wave = tid >> 6, lane = tid & 63;
  const int wrow = (wave >> 1) * 64, wcol = (wave & 1) * 64;
  const int lr = lane & 15, lk = (lane >> 4) * 8;

  f32x4 acc[4][4];
#pragma unroll
  for (int m = 0; m < 4; ++m)
#pragma unroll
    for (int n = 0; n < 4; ++n) acc[m][n] = (f32x4){0.f, 0.f, 0.f, 0.f};

  const int srow = tid >> 1, scol = (tid & 1) * 32;
  const bool avalid = (tileM + srow) < M;
  const ushort* Ap = A + (size_t)(tileM + srow) * K + scol;
  const ushort* Bp = Bt + (size_t)(tileN + srow) * K + scol;

  for (int k0 = 0; k0 < K; k0 += 64) {
    int4 ar[4], br[4];
    if (avalid) {
      const int4* p = reinterpret_cast<const int4*>(Ap + k0);
      ar[0] = p[0]; ar[1] = p[1]; ar[2] = p[2]; ar[3] = p[3];
    } else {
      int4 z; z.x = z.y = z.z = z.w = 0;
      ar[0] = z; ar[1] = z; ar[2] = z; ar[3] = z;
    }
    {
      const int4* p = reinterpret_cast<const int4*>(Bp + k0);
      br[0] = p[0]; br[1] = p[1]; br[2] = p[2]; br[3] = p[3];
    }
    __syncthreads();  // previous compute done reading LDS
    {
      int4* aw = reinterpret_cast<int4*>(&Alds[srow][scol]);
      aw[0] = ar[0]; aw[1] = ar[1]; aw[2] = ar[2]; aw[3] = ar[3];
      int4* bw = reinterpret_cast<int4*>(&Blds[srow][scol]);
      bw[0] = br[0]; bw[1] = br[1]; bw[2] = br[2]; bw[3] = br[3];
    }
    __syncthreads();
#pragma unroll
    for (int kk = 0; kk < 2; ++kk) {
      const int kb = kk * 32 + lk;
      bf16x8 af[4], bfr[4];
#pragma unroll
      for (int m = 0; m < 4; ++m)
        af[m] = *reinterpret_cast<const bf16x8*>(&Alds[wrow + m * 16 + lr][kb]);
#pragma unroll
      for (int n = 0; n < 4; ++n)
        bfr[n] = *reinterpret_cast<const bf16x8*>(&Blds[wcol + n * 16 + lr][kb]);
#pragma unroll
      for (int m = 0; m < 4; ++m)
#pragma unroll
        for (int n = 0; n < 4; ++n)
          acc[m][n] = __builtin_amdgcn_mfma_f32_16x16x32_bf16(af[m], bfr[n],
                                                              acc[m][n], 0, 0, 0);
    }
  }

  const int lr4 = (lane >> 4) * 4;
#pragma unroll
  for (int m = 0; m < 4; ++m) {
#pragma unroll
    for (int r = 0; r < 4; ++r) {
      const int row = tileM + wrow + m * 16 + lr4 + r;
      if (row >= M) continue;
#pragma unroll
      for (int n = 0; n < 4; ++n) {
        const int col = tileN + wcol + n * 16 + lr;
        float v = acc[m][n][r];
        if constexpr (EPI == EPI_BF16) {
          reinterpret_cast<ushort*>(Cptr)[(size_t)row * N + col] = f2bf(v);
        } else if constexpr (EPI == EPI_GELU_BF16) {
          v += bias[col];
          v = 0.5f * v * (1.0f + erff(v * 0.70710678118654752440f));
          reinterpret_cast<ushort*>(Cptr)[(size_t)row * N + col] = f2bf(v);
        } else if constexpr (EPI == EPI_RES_F32) {
          v += bias[col] + extra[(size_t)row * N + col];
          reinterpret_cast<float*>(Cptr)[(size_t)row * N + col] = v;
        } else {  // EPI_PATCH: row = b*576+p -> x row b*577+1+p
          const int bb = row / 576;
          const int p = row - bb * 576;
          v += bias[col] + extra[(size_t)(p + 1) * 768 + col];
          reinterpret_cast<float*>(Cptr)[(size_t)(row + bb + 1) * 768 + col] = v;
        }
      }
    }
  }
}

// ---------------------------------------------------------------------------
// Flash attention, f32 compute, bf16 qkv in / bf16 o out.
// Block = 256 thr (tx 0..15 over kv cols, ty 0..15 over q rows), per thread
// 4 q-rows x 4 cols. Q[64][68], K^T[64 d][68 col] (reused as P), V[64][68].
// SCALE = DIM^-0.5 = 768^-0.5 (per reference -- NOT DHEAD^-0.5).
// ---------------------------------------------------------------------------
__global__ __launch_bounds__(256) void attn_kernel(const ushort* __restrict__ qkv,
                                                   ushort* __restrict__ o) {
  __shared__ float sQ[64][68];
  __shared__ float sK[64][68];  // scores: K^T [d][col]; later P [qr][col]
  __shared__ float sV[64][68];
  const int bh = blockIdx.x;
  const int b = bh / 12, hh = bh % 12;
  const int q0 = blockIdx.y * 64;
  const int tid = threadIdx.x;
  const int tx = tid & 15, ty = tid >> 4;
  const ushort* base = qkv + (size_t)b * NTOK * 2304 + hh * 64;
  const float SC = 0.03608439182435161f;  // 768^-0.5

  {  // stage Q
    const int r = tid >> 2, c = (tid & 3) * 16;
    const int gq = q0 + r;
    float tmp[16];
    if (gq < NTOK) {
      const int4* p = reinterpret_cast<const int4*>(base + (size_t)gq * 2304 + c);
      bf8tof(p[0], tmp); bf8tof(p[1], tmp + 8);
    } else {
#pragma unroll
      for (int i = 0; i < 16; ++i) tmp[i] = 0.f;
    }
#pragma unroll
    for (int i = 0; i < 16; ++i) sQ[r][c + i] = tmp[i];
  }

  float mst[4], lst[4], acc[4][4];
#pragma unroll
  for (int i = 0; i < 4; ++i) {
    mst[i] = -1e30f; lst[i] = 0.f;
#pragma unroll
    for (int j = 0; j < 4; ++j) acc[i][j] = 0.f;
  }

  for (int t0 = 0; t0 < NTOK; t0 += 64) {
    __syncthreads();  // prev iter done reading sK(P)/sV; sQ visible after next
    {                 // stage K transposed: sK[d][col]
      const int n = tid & 63, d0 = (tid >> 6) * 16;
      const int gn = t0 + n;
      float tmp[16];
      if (gn < NTOK) {
        const int4* p = reinterpret_cast<const int4*>(base + (size_t)gn * 2304 + 768 + d0);
        bf8tof(p[0], tmp); bf8tof(p[1], tmp + 8);
      } else {
#pragma unroll
        for (int i = 0; i < 16; ++i) tmp[i] = 0.f;
      }
#pragma unroll
      for (int i = 0; i < 16; ++i) sK[d0 + i][n] = tmp[i];
      // stage V row-major
      const int r = tid >> 2, c = (tid & 3) * 16;
      const int gv = t0 + r;
      if (gv < NTOK) {
        const int4* p = reinterpret_cast<const int4*>(base + (size_t)gv * 2304 + 1536 + c);
        bf8tof(p[0], tmp); bf8tof(p[1], tmp + 8);
      } else {
#pragma unroll
        for (int i = 0; i < 16; ++i) tmp[i] = 0.f;
      }
#pragma unroll
      for (int i = 0; i < 16; ++i) sV[r][c + i] = tmp[i];
    }
    __syncthreads();

    float s[4][4];
#pragma unroll
    for (int i = 0; i < 4; ++i)
#pragma unroll
      for (int j = 0; j < 4; ++j) s[i][j] = 0.f;

#pragma unroll 4
    for (int d0 = 0; d0 < 64; d0 += 4) {
      const float4 kv0 = *reinterpret_cast<const float4*>(&sK[d0 + 0][tx * 4]);
      const float4 kv1 = *reinterpret_cast<const float4*>(&sK[d0 + 1][tx * 4]);
      const float4 kv2 = *reinterpret_cast<const float4*>(&sK[d0 + 2][tx * 4]);
      const float4 kv3 = *reinterpret_cast<const float4*>(&sK[d0 + 3][tx * 4]);
#pragma unroll
      for (int i = 0; i < 4; ++i) {
        const float4 qv = *reinterpret_cast<const float4*>(&sQ[ty * 4 + i][d0]);
        s[i][0] += qv.x * kv0.x + qv.y * kv1.x + qv.z * kv2.x + qv.w * kv3.x;
        s[i][1] += qv.x * kv0.y + qv.y * kv1.y + qv.z * kv2.y + qv.w * kv3.y;
        s[i][2] += qv.x * kv0.z + qv.y * kv1.z + qv.z * kv2.z + qv.w * kv3.z;
        s[i][3] += qv.x * kv0.w + qv.y * kv1.w + qv.z * kv2.w + qv.w * kv3.w;
      }
    }

    // online softmax
    float pm[4], al[4], rs[4];
#pragma unroll
    for (int i = 0; i < 4; ++i) {
#pragma unroll
      for (int j = 0; j < 4; ++j) {
        s[i][j] *= SC;
        if (t0 + tx * 4 + j >= NTOK) s[i][j] = -1e30f;
      }
      pm[i] = fmaxf(fmaxf(s[i][0], s[i][1]), fmaxf(s[i][2], s[i][3]));
    }
#pragma unroll
    for (int off = 1; off < 16; off <<= 1)
#pragma unroll
      for (int i = 0; i < 4; ++i) pm[i] = fmaxf(pm[i], __shfl_xor(pm[i], off));
#pragma unroll
    for (int i = 0; i < 4; ++i) {
      const float mn = fmaxf(mst[i], pm[i]);
      al[i] = __expf(mst[i] - mn);
      mst[i] = mn;
#pragma unroll
      for (int j = 0; j < 4; ++j) s[i][j] = __expf(s[i][j] - mn);
      rs[i] = s[i][0] + s[i][1] + s[i][2] + s[i][3];
    }
#pragma unroll
    for (int off = 1; off < 16; off <<= 1)
#pragma unroll
      for (int i = 0; i < 4; ++i) rs[i] += __shfl_xor(rs[i], off);
#pragma unroll
    for (int i = 0; i < 4; ++i) {
      lst[i] = lst[i] * al[i] + rs[i];
#pragma unroll
      for (int j = 0; j < 4; ++j) acc[i][j] *= al[i];
    }

    __syncthreads();  // all waves done reading sK as K^T
#pragma unroll
    for (int i = 0; i < 4; ++i)
      *reinterpret_cast<float4*>(&sK[ty * 4 + i][tx * 4]) =
          make_float4(s[i][0], s[i][1], s[i][2], s[i][3]);
    __syncthreads();

#pragma unroll 4
    for (int j0 = 0; j0 < 64; j0 += 4) {
      const float4 vv0 = *reinterpret_cast<const float4*>(&sV[j0 + 0][tx * 4]);
      const float4 vv1 = *reinterpret_cast<const float4*>(&sV[j0 + 1][tx * 4]);
      const float4 vv2 = *reinterpret_cast<const float4*>(&sV[j0 + 2][tx * 4]);
      const float4 vv3 = *reinterpret_cast<const float4*>(&sV[j0 + 3][tx * 4]);
#pragma unroll
      for (int i = 0; i < 4; ++i) {
        const float4 pv = *reinterpret_cast<const float4*>(&sK[ty * 4 + i][j0]);
        acc[i][0] += pv.x * vv0.x + pv.y * vv1.x + pv.z * vv2.x + pv.w * vv3.x;
        acc[i][1] += pv.x * vv0.y + pv.y * vv1.y + pv.z * vv2.y + pv.w * vv3.y;
        acc[i][2] += pv.x * vv0.z + pv.y * vv1.z + pv.z * vv2.z + pv.w * vv3.z;
        acc[i][3] += pv.x * vv0.w + pv.y * vv1.w + pv.z * vv2.w + pv.w * vv3.w;
      }
    }
  }

#pragma unroll
  for (int i = 0; i < 4; ++i) {
    const int n = q0 + ty * 4 + i;
    if (n >= NTOK) continue;
    const float inv = 1.0f / lst[i];
    ushort4 u;
    u.x = f2bf(acc[i][0] * inv);
    u.y = f2bf(acc[i][1] * inv);
    u.z = f2bf(acc[i][2] * inv);
    u.w = f2bf(acc[i][3] * inv);
    *reinterpret_cast<ushort4*>(o + (size_t)(b * NTOK + n) * 768 + hh * 64 + tx * 4) = u;
  }
}

// ---------------------------------------------------------------------------
// Head: LN(cls rows) @ head_w (768x1000) + head_b -> out (16x1000) f32
// ---------------------------------------------------------------------------
__global__ __launch_bounds__(256) void head_kernel(const float* __restrict__ x,
                                                   const float* __restrict__ lw,
                                                   const float* __restrict__ lb,
                                                   const float* __restrict__ hw,
                                                   const float* __restrict__ hb,
                                                   float* __restrict__ out) {
  __shared__ float srow[768];
  __shared__ float sred[8];
  const int b = blockIdx.x, tid = threadIdx.x;
  const float* xr = x + (size_t)b * NTOK * 768;
  for (int i = tid; i < 768; i += 256) srow[i] = xr[i];
  __syncthreads();
  float part = srow[tid] + srow[tid + 256] + srow[tid + 512];
#pragma unroll
  for (int off = 32; off; off >>= 1) part += __shfl_xor(part, off);
  if ((tid & 63) == 0) sred[tid >> 6] = part;
  __syncthreads();
  const float mu = (sred[0] + sred[1] + sred[2] + sred[3]) * (1.0f / 768.0f);
  const float d0 = srow[tid] - mu, d1 = srow[tid + 256] - mu, d2 = srow[tid + 512] - mu;
  float vp = d0 * d0 + d1 * d1 + d2 * d2;
#pragma unroll
  for (int off = 32; off; off >>= 1) vp += __shfl_xor(vp, off);
  if ((tid & 63) == 0) sred[4 + (tid >> 6)] = vp;
  __syncthreads();
  const float rstd = rsqrtf((sred[4] + sred[5] + sred[6] + sred[7]) * (1.0f / 768.0f) + 1e-5f);
  for (int i = tid; i < 768; i += 256) srow[i] = (srow[i] - mu) * rstd * lw[i] + lb[i];
  __syncthreads();
  const int c = blockIdx.y * 250 + tid;
  if (tid < 250 && c < 1000) {
    float a = 0.f;
#pragma unroll 4
    for (int k = 0; k < 768; ++k) a += srow[k] * hw[(size_t)k * 1000 + c];
    out[b * 1000 + c] = a + hb[c];
  }
}

// ---------------------------------------------------------------------------
extern "C" void kernel_launch(void* const* d_in, const int* in_sizes, int n_in,
                              void* d_out, int out_size, void* d_ws, size_t ws_size,
                              hipStream_t stream) {
  const float* img     = (const float*)d_in[0];
  const float* patch_w = (const float*)d_in[1];
  const float* patch_b = (const float*)d_in[2];
  const float* pos_emb = (const float*)d_in[3];
  const float* cls_tok = (const float*)d_in[4];
  const float* ln1_w   = (const float*)d_in[5];
  const float* ln1_b   = (const float*)d_in[6];
  const float* qkv_w   = (const float*)d_in[7];
  const float* out_w   = (const float*)d_in[8];
  const float* out_b   = (const float*)d_in[9];
  const float* ln2_w   = (const float*)d_in[10];
  const float* ln2_b   = (const float*)d_in[11];
  const float* ff1_w   = (const float*)d_in[12];
  const float* ff1_b   = (const float*)d_in[13];
  const float* ff2_w   = (const float*)d_in[14];
  const float* ff2_b   = (const float*)d_in[15];
  const float* hln_w   = (const float*)d_in[16];
  const float* hln_b   = (const float*)d_in[17];
  const float* head_w  = (const float*)d_in[18];
  const float* head_b  = (const float*)d_in[19];
  float* outp = (float*)d_out;

  char* wsp = (char*)d_ws;
  auto alloc = [&](size_t bytes) {
    char* p = wsp;
    wsp += (bytes + 255) & ~(size_t)255;
    return p;
  };
  float*  x    = (float*) alloc((size_t)9232 * 768 * 4);   // residual stream
  ushort* h    = (ushort*)alloc((size_t)9232 * 768 * 2);   // LN out / attn out
  ushort* qkvb = (ushort*)alloc((size_t)9232 * 2304 * 2);  // qkv bf16
  ushort* mlp  = (ushort*)alloc((size_t)9232 * 3072 * 2);  // gelu out (alias: apatch)
  ushort* wq   = (ushort*)alloc((size_t)768 * 2304 * 2);   // (alias: wpatch)
  ushort* wo   = (ushort*)alloc((size_t)768 * 768 * 2);
  ushort* w1   = (ushort*)alloc((size_t)768 * 3072 * 2);
  ushort* w2   = (ushort*)alloc((size_t)3072 * 768 * 2);
  ushort* apatch = mlp;
  ushort* wpatch = wq;

  // ---- patch embedding ----
  convt_kernel<<<dim3(24, 24), 256, 0, stream>>>(patch_w, wpatch, 768, 768);
  im2col_kernel<<<27648, 256, 0, stream>>>(img, apatch);
  gemm_kernel<EPI_PATCH><<<dim3(72, 6), 256, 0, stream>>>(
      apatch, wpatch, patch_b, pos_emb, x, 9216, 768, 768);
  clspos_kernel<<<48, 256, 0, stream>>>(cls_tok, pos_emb, x);

  // ---- transformer layers ----
  for (int l = 0; l < 12; ++l) {
    ln_kernel<<<9232, 64, 0, stream>>>(x, ln1_w + l * 768, ln1_b + l * 768, h);
    convt_kernel<<<dim3(24, 72), 256, 0, stream>>>(qkv_w + (size_t)l * 768 * 2304, wq, 768, 2304);
    gemm_kernel<EPI_BF16><<<dim3(73, 18), 256, 0, stream>>>(
        h, wq, nullptr, nullptr, qkvb, 9232, 2304, 768);
    attn_kernel<<<dim3(192, 10), 256, 0, stream>>>(qkvb, h);  // o -> h
    convt_kernel<<<dim3(24, 24), 256, 0, stream>>>(out_w + (size_t)l * 768 * 768, wo, 768, 768);
    gemm_kernel<EPI_RES_F32><<<dim3(73, 6), 256, 0, stream>>>(
        h, wo, out_b + l * 768, x, x, 9232, 768, 768);
    ln_kernel<<<9232, 64, 0, stream>>>(x, ln2_w + l * 768, ln2_b + l * 768, h);
    convt_kernel<<<dim3(24, 96), 256, 0, stream>>>(ff1_w + (size_t)l * 768 * 3072, w1, 768, 3072);
    gemm_kernel<EPI_GELU_BF16><<<dim3(73, 24), 256, 0, stream>>>(
        h, w1, ff1_b + l * 3072, nullptr, mlp, 9232, 3072, 768);
    convt_kernel<<<dim3(96, 24), 256, 0, stream>>>(ff2_w + (size_t)l * 3072 * 768, w2, 3072, 768);
    gemm_kernel<EPI_RES_F32><<<dim3(73, 6), 256, 0, stream>>>(
        mlp, w2, ff2_b + l * 768, x, x, 9232, 768, 3072);
  }

  // ---- classification head ----
  head_kernel<<<dim3(16, 4), 256, 0, stream>>>(x, hln_w, hln_b, head_w, head_b, outp);
}

// Round 3
// 4965.966 us; speedup vs baseline: 1.9689x; 1.9689x over previous
//
#include <hip/hip_runtime.h>
#include <cstdint>

// ============================================================================
// ViT forward, MI355X round 2.
//   R2 changes vs R1:
//   - attn_kernel: f32 VALU flash -> bf16 MFMA flash (QK^T and PV on
//     mfma_f32_16x16x32_bf16, softmax in C-layout regs, P via per-wave LDS).
//   - gemm_kernel: reg-staged LDS -> m97 structure (linear LDS [128][32],
//     global_load_lds width=16, BK=32, 2-barrier loop).
// ============================================================================

typedef __attribute__((ext_vector_type(8))) short bf16x8;
typedef __attribute__((ext_vector_type(4))) float f32x4;

#define NTOK 577

__device__ __forceinline__ ushort f2bf(float f) {
  union { float f; unsigned int u; } x; x.f = f;
  unsigned int r = x.u + 0x7fffu + ((x.u >> 16) & 1u);  // RNE
  return (ushort)(r >> 16);
}

__device__ __forceinline__ void gload_lds16(const ushort* g, ushort* l) {
  __builtin_amdgcn_global_load_lds(
      (const __attribute__((address_space(1))) unsigned int*)g,
      (__attribute__((address_space(3))) unsigned int*)l, 16, 0, 0);
}

// ---------------------------------------------------------------------------
// f32 W[K][N]  ->  bf16 Wt[N][K]   (tiled transpose, coalesced both sides)
// ---------------------------------------------------------------------------
__global__ __launch_bounds__(256) void convt_kernel(const float* __restrict__ W,
                                                    ushort* __restrict__ Wt,
                                                    int K, int N) {
  __shared__ float t[32][33];
  const int kb = blockIdx.x * 32, nb = blockIdx.y * 32;
  const int tx = threadIdx.x & 31, ty = threadIdx.x >> 5;
#pragma unroll
  for (int i = 0; i < 32; i += 8)
    t[ty + i][tx] = W[(size_t)(kb + ty + i) * N + (nb + tx)];
  __syncthreads();
#pragma unroll
  for (int i = 0; i < 32; i += 8)
    Wt[(size_t)(nb + ty + i) * K + (kb + tx)] = f2bf(t[tx][ty + i]);
}

// ---------------------------------------------------------------------------
// im2col: img (B,3,384,384) f32 -> Apatch (9216 x 768) bf16
// ---------------------------------------------------------------------------
__global__ __launch_bounds__(256) void im2col_kernel(const float* __restrict__ img,
                                                     ushort* __restrict__ Ap) {
  const int idx = blockIdx.x * 256 + threadIdx.x;  // 9216*768 exactly
  const int j = idx % 768;
  const int m = idx / 768;
  const int c = j % 3;
  const int q = j / 3;
  const int px = q & 15, py = q >> 4;
  const int b = m / 576, p = m % 576;
  const int gy = p / 24, gx = p % 24;
  const float v = img[((size_t)(b * 3 + c) * 384 + (gy * 16 + py)) * 384 + (gx * 16 + px)];
  Ap[idx] = f2bf(v);
}

__global__ void clspos_kernel(const float* __restrict__ cls_tok,
                              const float* __restrict__ pos,
                              float* __restrict__ x) {
  const int i = blockIdx.x * 256 + threadIdx.x;  // 16*768
  const int b = i / 768, d = i % 768;
  x[(size_t)b * NTOK * 768 + d] = cls_tok[d] + pos[d];
}

// ---------------------------------------------------------------------------
// LayerNorm row kernel: x f32 row (768) -> bf16 out row. 1 wave per row.
// ---------------------------------------------------------------------------
__global__ __launch_bounds__(64) void ln_kernel(const float* __restrict__ x,
                                                const float* __restrict__ w,
                                                const float* __restrict__ bb,
                                                ushort* __restrict__ out) {
  const int row = blockIdx.x, lane = threadIdx.x;
  const float4* xr = reinterpret_cast<const float4*>(x + (size_t)row * 768);
  const float4 v0 = xr[lane], v1 = xr[lane + 64], v2 = xr[lane + 128];
  float vals[12] = {v0.x, v0.y, v0.z, v0.w, v1.x, v1.y, v1.z, v1.w,
                    v2.x, v2.y, v2.z, v2.w};
  float s = 0.f;
#pragma unroll
  for (int i = 0; i < 12; ++i) s += vals[i];
#pragma unroll
  for (int o = 32; o; o >>= 1) s += __shfl_xor(s, o);
  const float mu = s * (1.0f / 768.0f);
  float q = 0.f;
#pragma unroll
  for (int i = 0; i < 12; ++i) { const float d = vals[i] - mu; q += d * d; }
#pragma unroll
  for (int o = 32; o; o >>= 1) q += __shfl_xor(q, o);
  const float rstd = rsqrtf(q * (1.0f / 768.0f) + 1e-5f);
  const float4* w4 = reinterpret_cast<const float4*>(w);
  const float4* b4 = reinterpret_cast<const float4*>(bb);
  ushort* orow = out + (size_t)row * 768;
#pragma unroll
  for (int ch = 0; ch < 3; ++ch) {
    const float4 wv = w4[lane + ch * 64];
    const float4 bv = b4[lane + ch * 64];
    ushort4 u;
    u.x = f2bf((vals[ch * 4 + 0] - mu) * rstd * wv.x + bv.x);
    u.y = f2bf((vals[ch * 4 + 1] - mu) * rstd * wv.y + bv.y);
    u.z = f2bf((vals[ch * 4 + 2] - mu) * rstd * wv.z + bv.z);
    u.w = f2bf((vals[ch * 4 + 3] - mu) * rstd * wv.w + bv.w);
    *reinterpret_cast<ushort4*>(orow + ch * 256 + lane * 4) = u;
  }
}

// ---------------------------------------------------------------------------
// MFMA GEMM, m97 structure: C(MxN) = A(MxK bf16) @ Bt^T (Bt is N x K bf16).
// 128x128 tile, BK=32, linear LDS [128][32], global_load_lds width 16.
// Tail rows (>=M) may stage garbage (incl. NaN); MFMA keeps NaN confined to
// those output rows, which the epilogue discards.
// ---------------------------------------------------------------------------
constexpr int EPI_BF16 = 0;       // C = acc                     -> bf16
constexpr int EPI_GELU_BF16 = 1;  // C = gelu(acc + bias)        -> bf16
constexpr int EPI_RES_F32 = 2;    // C = acc + bias + extra[r,c] -> f32
constexpr int EPI_PATCH = 3;      // x[row+b+1] = acc + patch_b + pos[p+1]

template <int EPI>
__global__ __launch_bounds__(256) void gemm_kernel(
    const ushort* __restrict__ A, const ushort* __restrict__ Bt,
    const float* __restrict__ bias, const float* __restrict__ extra,
    void* __restrict__ Cptr, int M, int N, int K) {
  __shared__ ushort Alds[128 * 32];
  __shared__ ushort Blds[128 * 32];
  const int tid = threadIdx.x;
  const int tileM = blockIdx.x * 128, tileN = blockIdx.y * 128;
  const int wave = tid >> 6, lane = tid & 63;
  const int wrow = (wave >> 1) * 64, wcol = (wave & 1) * 64;
  const int lr = lane & 15, lk = (lane >> 4) * 8;

  f32x4 acc[4][4];
#pragma unroll
  for (int m = 0; m < 4; ++m)
#pragma unroll
    for (int n = 0; n < 4; ++n) acc[m][n] = (f32x4){0.f, 0.f, 0.f, 0.f};

  // Staging: wave w covers chunks {2w, 2w+1}; chunk = 16 rows x 32 cols
  // (1 KiB). HW writes lane's 16 B at ldsbase + lane*16 -> row = chunk*16 +
  // lane/4, col = (lane&3)*8. Global source mirrors that mapping per lane.
  const int srow = wave * 32 + (lane >> 2);
  const int scol = (lane & 3) * 8;
  const ushort* Ap = A + (size_t)(tileM + srow) * K + scol;
  const ushort* Bp = Bt + (size_t)(tileN + srow) * K + scol;
  ushort* Al0 = &Alds[(wave * 2 + 0) * 512];
  ushort* Al1 = &Alds[(wave * 2 + 1) * 512];
  ushort* Bl0 = &Blds[(wave * 2 + 0) * 512];
  ushort* Bl1 = &Blds[(wave * 2 + 1) * 512];
  const size_t cstride = (size_t)16 * K;  // 16 rows

  for (int k0 = 0; k0 < K; k0 += 32) {
    __syncthreads();  // previous compute done reading LDS
    gload_lds16(Ap + k0, Al0);
    gload_lds16(Ap + k0 + cstride, Al1);
    gload_lds16(Bp + k0, Bl0);
    gload_lds16(Bp + k0 + cstride, Bl1);
    __syncthreads();  // compiler drains vmcnt before barrier

    bf16x8 af[4], bfr[4];
#pragma unroll
    for (int m = 0; m < 4; ++m)
      af[m] = *reinterpret_cast<const bf16x8*>(&Alds[(wrow + m * 16 + lr) * 32 + lk]);
#pragma unroll
    for (int n = 0; n < 4; ++n)
      bfr[n] = *reinterpret_cast<const bf16x8*>(&Blds[(wcol + n * 16 + lr) * 32 + lk]);
#pragma unroll
    for (int m = 0; m < 4; ++m)
#pragma unroll
      for (int n = 0; n < 4; ++n)
        acc[m][n] = __builtin_amdgcn_mfma_f32_16x16x32_bf16(af[m], bfr[n],
                                                            acc[m][n], 0, 0, 0);
  }

  const int lr4 = (lane >> 4) * 4;
#pragma unroll
  for (int m = 0; m < 4; ++m) {
#pragma unroll
    for (int r = 0; r < 4; ++r) {
      const int row = tileM + wrow + m * 16 + lr4 + r;
      if (row >= M) continue;
#pragma unroll
      for (int n = 0; n < 4; ++n) {
        const int col = tileN + wcol + n * 16 + lr;
        float v = acc[m][n][r];
        if constexpr (EPI == EPI_BF16) {
          reinterpret_cast<ushort*>(Cptr)[(size_t)row * N + col] = f2bf(v);
        } else if constexpr (EPI == EPI_GELU_BF16) {
          v += bias[col];
          v = 0.5f * v * (1.0f + erff(v * 0.70710678118654752440f));
          reinterpret_cast<ushort*>(Cptr)[(size_t)row * N + col] = f2bf(v);
        } else if constexpr (EPI == EPI_RES_F32) {
          v += bias[col] + extra[(size_t)row * N + col];
          reinterpret_cast<float*>(Cptr)[(size_t)row * N + col] = v;
        } else {  // EPI_PATCH: row = b*576+p -> x row b*577+1+p
          const int bb = row / 576;
          const int p = row - bb * 576;
          v += bias[col] + extra[(size_t)(p + 1) * 768 + col];
          reinterpret_cast<float*>(Cptr)[(size_t)(row + bb + 1) * 768 + col] = v;
        }
      }
    }
  }
}

// ---------------------------------------------------------------------------
// MFMA flash attention. Block = 256 thr = 4 waves; wave w owns q rows
// q0 + w*16 .. +15. KV tile = 64 keys. All matmuls mfma_f32_16x16x32_bf16.
//   QK^T: A = Q frags (regs, hoisted), B from sK[key][d] row-major.
//   softmax: C-layout regs (row = (lane>>4)*4+reg, col = n*16 + (lane&15)),
//            row-reduce via __shfl_xor over the 16 col-lanes.
//   P -> per-wave sP[16][72] bf16 (A-fragment layout); no barrier needed —
//        same-wave ds_write -> ds_read ordered by lgkmcnt.
//   PV: A = P frags, B from sVt[d][key] (V transposed at staging).
// SCALE = DIM^-0.5 = 768^-0.5 (reference scales by DIM, not DHEAD).
// ---------------------------------------------------------------------------
__global__ __launch_bounds__(256) void attn_kernel(const ushort* __restrict__ qkv,
                                                   ushort* __restrict__ o) {
  __shared__ ushort sK[64][72];
  __shared__ ushort sVt[64][72];
  __shared__ ushort sP[4][16][72];
  const int bh = blockIdx.x;
  const int b = bh / 12, hh = bh % 12;
  const int q0 = blockIdx.y * 64;
  const int tid = threadIdx.x;
  const int wave = tid >> 6, lane = tid & 63;
  const int lr = lane & 15;   // A-frag row / B-frag col / C col
  const int lg = lane >> 4;   // k-group (frag) / C row-group
  const ushort* base = qkv + (size_t)b * NTOK * 2304 + hh * 64;
  const float SC = 0.03608439182435161f;  // 768^-0.5

  // Q fragments: rows q0 + wave*16 + lr, k-slices d 0-31 / 32-63
  bf16x8 qf[2];
  {
    const int qrow = q0 + wave * 16 + lr;
    if (qrow < NTOK) {
      const ushort* qp = base + (size_t)qrow * 2304 + lg * 8;
      qf[0] = *reinterpret_cast<const bf16x8*>(qp);
      qf[1] = *reinterpret_cast<const bf16x8*>(qp + 32);
    } else {
      qf[0] = (bf16x8){0, 0, 0, 0, 0, 0, 0, 0};
      qf[1] = qf[0];
    }
  }

  float mst[4], lst[4];
  f32x4 oacc[4];
#pragma unroll
  for (int i = 0; i < 4; ++i) {
    mst[i] = -1e30f; lst[i] = 0.f;
    oacc[i] = (f32x4){0.f, 0.f, 0.f, 0.f};
  }

  const int skey = tid >> 2;        // 0..63
  const int sd = (tid & 3) * 16;    // 0,16,32,48

  for (int t0 = 0; t0 < NTOK; t0 += 64) {
    __syncthreads();  // all waves done reading sK/sVt of previous tile
    {
      const int gk = t0 + skey;
      int4 k0v, k1v, v0v, v1v;
      if (gk < NTOK) {
        const int4* kp = reinterpret_cast<const int4*>(base + (size_t)gk * 2304 + 768 + sd);
        k0v = kp[0]; k1v = kp[1];
        const int4* vp = reinterpret_cast<const int4*>(base + (size_t)gk * 2304 + 1536 + sd);
        v0v = vp[0]; v1v = vp[1];
      } else {
        int4 z; z.x = z.y = z.z = z.w = 0;
        k0v = k1v = v0v = v1v = z;
      }
      *reinterpret_cast<int4*>(&sK[skey][sd]) = k0v;
      *reinterpret_cast<int4*>(&sK[skey][sd + 8]) = k1v;
      const ushort* vs = reinterpret_cast<const ushort*>(&v0v);
#pragma unroll
      for (int i = 0; i < 8; ++i) sVt[sd + i][skey] = vs[i];
      const ushort* vs2 = reinterpret_cast<const ushort*>(&v1v);
#pragma unroll
      for (int i = 0; i < 8; ++i) sVt[sd + 8 + i][skey] = vs2[i];
    }
    __syncthreads();

    // ---- S = Q K^T (16 x 64 per wave) ----
    f32x4 sacc[4];
#pragma unroll
    for (int n = 0; n < 4; ++n) sacc[n] = (f32x4){0.f, 0.f, 0.f, 0.f};
#pragma unroll
    for (int n = 0; n < 4; ++n) {
      const bf16x8 kf0 = *reinterpret_cast<const bf16x8*>(&sK[n * 16 + lr][lg * 8]);
      const bf16x8 kf1 = *reinterpret_cast<const bf16x8*>(&sK[n * 16 + lr][32 + lg * 8]);
      sacc[n] = __builtin_amdgcn_mfma_f32_16x16x32_bf16(qf[0], kf0, sacc[n], 0, 0, 0);
      sacc[n] = __builtin_amdgcn_mfma_f32_16x16x32_bf16(qf[1], kf1, sacc[n], 0, 0, 0);
    }

    // ---- online softmax on C-layout regs ----
    float s[4][4], pm[4];
#pragma unroll
    for (int reg = 0; reg < 4; ++reg) pm[reg] = -1e30f;
#pragma unroll
    for (int n = 0; n < 4; ++n)
#pragma unroll
      for (int reg = 0; reg < 4; ++reg) {
        float v = sacc[n][reg] * SC;
        if (t0 + n * 16 + lr >= NTOK) v = -1e30f;
        s[n][reg] = v;
        pm[reg] = fmaxf(pm[reg], v);
      }
#pragma unroll
    for (int off = 1; off < 16; off <<= 1)
#pragma unroll
      for (int reg = 0; reg < 4; ++reg) pm[reg] = fmaxf(pm[reg], __shfl_xor(pm[reg], off));

    float al[4], rs[4];
#pragma unroll
    for (int reg = 0; reg < 4; ++reg) {
      const float mn = fmaxf(mst[reg], pm[reg]);
      al[reg] = __expf(mst[reg] - mn);
      mst[reg] = mn;
      rs[reg] = 0.f;
    }
#pragma unroll
    for (int n = 0; n < 4; ++n)
#pragma unroll
      for (int reg = 0; reg < 4; ++reg) {
        s[n][reg] = __expf(s[n][reg] - mst[reg]);
        rs[reg] += s[n][reg];
      }
#pragma unroll
    for (int off = 1; off < 16; off <<= 1)
#pragma unroll
      for (int reg = 0; reg < 4; ++reg) rs[reg] += __shfl_xor(rs[reg], off);
#pragma unroll
    for (int reg = 0; reg < 4; ++reg) {
      lst[reg] = lst[reg] * al[reg] + rs[reg];
#pragma unroll
      for (int n = 0; n < 4; ++n) oacc[n][reg] *= al[reg];
    }

    // ---- P -> per-wave LDS (row = lg*4+reg, col = n*16+lr) ----
#pragma unroll
    for (int n = 0; n < 4; ++n)
#pragma unroll
      for (int reg = 0; reg < 4; ++reg)
        sP[wave][lg * 4 + reg][n * 16 + lr] = f2bf(s[n][reg]);

    // ---- O += P V ----
    const bf16x8 pf0 = *reinterpret_cast<const bf16x8*>(&sP[wave][lr][lg * 8]);
    const bf16x8 pf1 = *reinterpret_cast<const bf16x8*>(&sP[wave][lr][32 + lg * 8]);
#pragma unroll
    for (int n = 0; n < 4; ++n) {
      const bf16x8 vf0 = *reinterpret_cast<const bf16x8*>(&sVt[n * 16 + lr][lg * 8]);
      const bf16x8 vf1 = *reinterpret_cast<const bf16x8*>(&sVt[n * 16 + lr][32 + lg * 8]);
      oacc[n] = __builtin_amdgcn_mfma_f32_16x16x32_bf16(pf0, vf0, oacc[n], 0, 0, 0);
      oacc[n] = __builtin_amdgcn_mfma_f32_16x16x32_bf16(pf1, vf1, oacc[n], 0, 0, 0);
    }
  }

  // ---- output: rows q0 + wave*16 + lg*4 + reg, cols hh*64 + n*16 + lr ----
#pragma unroll
  for (int reg = 0; reg < 4; ++reg) {
    const int q = q0 + wave * 16 + lg * 4 + reg;
    if (q >= NTOK) continue;
    const float inv = 1.0f / lst[reg];
    ushort* op = o + (size_t)(b * NTOK + q) * 768 + hh * 64;
#pragma unroll
    for (int n = 0; n < 4; ++n) op[n * 16 + lr] = f2bf(oacc[n][reg] * inv);
  }
}

// ---------------------------------------------------------------------------
// Head: LN(cls rows) @ head_w (768x1000) + head_b -> out (16x1000) f32
// ---------------------------------------------------------------------------
__global__ __launch_bounds__(256) void head_kernel(const float* __restrict__ x,
                                                   const float* __restrict__ lw,
                                                   const float* __restrict__ lb,
                                                   const float* __restrict__ hw,
                                                   const float* __restrict__ hb,
                                                   float* __restrict__ out) {
  __shared__ float srow[768];
  __shared__ float sred[8];
  const int b = blockIdx.x, tid = threadIdx.x;
  const float* xr = x + (size_t)b * NTOK * 768;
  for (int i = tid; i < 768; i += 256) srow[i] = xr[i];
  __syncthreads();
  float part = srow[tid] + srow[tid + 256] + srow[tid + 512];
#pragma unroll
  for (int off = 32; off; off >>= 1) part += __shfl_xor(part, off);
  if ((tid & 63) == 0) sred[tid >> 6] = part;
  __syncthreads();
  const float mu = (sred[0] + sred[1] + sred[2] + sred[3]) * (1.0f / 768.0f);
  const float d0 = srow[tid] - mu, d1 = srow[tid + 256] - mu, d2 = srow[tid + 512] - mu;
  float vp = d0 * d0 + d1 * d1 + d2 * d2;
#pragma unroll
  for (int off = 32; off; off >>= 1) vp += __shfl_xor(vp, off);
  if ((tid & 63) == 0) sred[4 + (tid >> 6)] = vp;
  __syncthreads();
  const float rstd = rsqrtf((sred[4] + sred[5] + sred[6] + sred[7]) * (1.0f / 768.0f) + 1e-5f);
  for (int i = tid; i < 768; i += 256) srow[i] = (srow[i] - mu) * rstd * lw[i] + lb[i];
  __syncthreads();
  const int c = blockIdx.y * 250 + tid;
  if (tid < 250 && c < 1000) {
    float a = 0.f;
#pragma unroll 4
    for (int k = 0; k < 768; ++k) a += srow[k] * hw[(size_t)k * 1000 + c];
    out[b * 1000 + c] = a + hb[c];
  }
}

// ---------------------------------------------------------------------------
extern "C" void kernel_launch(void* const* d_in, const int* in_sizes, int n_in,
                              void* d_out, int out_size, void* d_ws, size_t ws_size,
                              hipStream_t stream) {
  const float* img     = (const float*)d_in[0];
  const float* patch_w = (const float*)d_in[1];
  const float* patch_b = (const float*)d_in[2];
  const float* pos_emb = (const float*)d_in[3];
  const float* cls_tok = (const float*)d_in[4];
  const float* ln1_w   = (const float*)d_in[5];
  const float* ln1_b   = (const float*)d_in[6];
  const float* qkv_w   = (const float*)d_in[7];
  const float* out_w   = (const float*)d_in[8];
  const float* out_b   = (const float*)d_in[9];
  const float* ln2_w   = (const float*)d_in[10];
  const float* ln2_b   = (const float*)d_in[11];
  const float* ff1_w   = (const float*)d_in[12];
  const float* ff1_b   = (const float*)d_in[13];
  const float* ff2_w   = (const float*)d_in[14];
  const float* ff2_b   = (const float*)d_in[15];
  const float* hln_w   = (const float*)d_in[16];
  const float* hln_b   = (const float*)d_in[17];
  const float* head_w  = (const float*)d_in[18];
  const float* head_b  = (const float*)d_in[19];
  float* outp = (float*)d_out;

  char* wsp = (char*)d_ws;
  auto alloc = [&](size_t bytes) {
    char* p = wsp;
    wsp += (bytes + 255) & ~(size_t)255;
    return p;
  };
  float*  x    = (float*) alloc((size_t)9232 * 768 * 4);   // residual stream
  ushort* h    = (ushort*)alloc((size_t)9232 * 768 * 2);   // LN out / attn out
  ushort* qkvb = (ushort*)alloc((size_t)9232 * 2304 * 2);  // qkv bf16
  ushort* mlp  = (ushort*)alloc((size_t)9232 * 3072 * 2);  // gelu out (alias: apatch)
  ushort* wq   = (ushort*)alloc((size_t)768 * 2304 * 2);   // (alias: wpatch)
  ushort* wo   = (ushort*)alloc((size_t)768 * 768 * 2);
  ushort* w1   = (ushort*)alloc((size_t)768 * 3072 * 2);
  ushort* w2   = (ushort*)alloc((size_t)3072 * 768 * 2);
  ushort* apatch = mlp;
  ushort* wpatch = wq;

  // ---- patch embedding ----
  convt_kernel<<<dim3(24, 24), 256, 0, stream>>>(patch_w, wpatch, 768, 768);
  im2col_kernel<<<27648, 256, 0, stream>>>(img, apatch);
  gemm_kernel<EPI_PATCH><<<dim3(72, 6), 256, 0, stream>>>(
      apatch, wpatch, patch_b, pos_emb, x, 9216, 768, 768);
  clspos_kernel<<<48, 256, 0, stream>>>(cls_tok, pos_emb, x);

  // ---- transformer layers ----
  for (int l = 0; l < 12; ++l) {
    ln_kernel<<<9232, 64, 0, stream>>>(x, ln1_w + l * 768, ln1_b + l * 768, h);
    convt_kernel<<<dim3(24, 72), 256, 0, stream>>>(qkv_w + (size_t)l * 768 * 2304, wq, 768, 2304);
    gemm_kernel<EPI_BF16><<<dim3(73, 18), 256, 0, stream>>>(
        h, wq, nullptr, nullptr, qkvb, 9232, 2304, 768);
    attn_kernel<<<dim3(192, 10), 256, 0, stream>>>(qkvb, h);  // o -> h
    convt_kernel<<<dim3(24, 24), 256, 0, stream>>>(out_w + (size_t)l * 768 * 768, wo, 768, 768);
    gemm_kernel<EPI_RES_F32><<<dim3(73, 6), 256, 0, stream>>>(
        h, wo, out_b + l * 768, x, x, 9232, 768, 768);
    ln_kernel<<<9232, 64, 0, stream>>>(x, ln2_w + l * 768, ln2_b + l * 768, h);
    convt_kernel<<<dim3(24, 96), 256, 0, stream>>>(ff1_w + (size_t)l * 768 * 3072, w1, 768, 3072);
    gemm_kernel<EPI_GELU_BF16><<<dim3(73, 24), 256, 0, stream>>>(
        h, w1, ff1_b + l * 3072, nullptr, mlp, 9232, 3072, 768);
    convt_kernel<<<dim3(96, 24), 256, 0, stream>>>(ff2_w + (size_t)l * 3072 * 768, w2, 3072, 768);
    gemm_kernel<EPI_RES_F32><<<dim3(73, 6), 256, 0, stream>>>(
        mlp, w2, ff2_b + l * 768, x, x, 9232, 768, 3072);
  }

  // ---- classification head ----
  head_kernel<<<dim3(16, 4), 256, 0, stream>>>(x, hln_w, hln_b, head_w, head_b, outp);
}

// Round 5
// 4638.499 us; speedup vs baseline: 2.1079x; 1.0706x over previous
//
#include <hip/hip_runtime.h>
#include <cstdint>

// ============================================================================
// ViT forward, MI355X round 4.
//   R4 change vs R3 (tripwire fix): gemm8_kernel's last K-tile is peeled with
//   drain waits vmcnt(4)/vmcnt(2)/vmcnt(0). R3's uniform vmcnt(4) became a
//   no-op once the stage queue drained (last tile issues no loads), so the
//   final K-step's ds_reads raced the in-flight global_load_lds -> the
//   launch-vs-graph divergence. Main loop now stages unconditionally.
// ============================================================================

typedef __attribute__((ext_vector_type(8))) short bf16x8;
typedef __attribute__((ext_vector_type(4))) float f32x4;

#define NTOK 577

__device__ __forceinline__ ushort f2bf(float f) {
  union { float f; unsigned int u; } x; x.f = f;
  unsigned int r = x.u + 0x7fffu + ((x.u >> 16) & 1u);  // RNE
  return (ushort)(r >> 16);
}

__device__ __forceinline__ void gload_lds16(const ushort* g, ushort* l) {
  __builtin_amdgcn_global_load_lds(
      (const __attribute__((address_space(1))) unsigned int*)g,
      (__attribute__((address_space(3))) unsigned int*)l, 16, 0, 0);
}

#define VMCNT4 asm volatile("s_waitcnt vmcnt(4)" ::: "memory")
#define VMCNT2 asm volatile("s_waitcnt vmcnt(2)" ::: "memory")
#define VMCNT0 asm volatile("s_waitcnt vmcnt(0)" ::: "memory")
#define LGKM0  asm volatile("s_waitcnt lgkmcnt(0)" ::: "memory")
#define SCHED0 __builtin_amdgcn_sched_barrier(0)
#define BARRIER __builtin_amdgcn_s_barrier()

// rotation swizzle: logical 16B-granule g at row -> physical granule
__device__ __forceinline__ int gsw(int row) {
  return (row & 7) + 2 * ((row >> 4) & 3);
}

// ---------------------------------------------------------------------------
// f32 W[K][N]  ->  bf16 Wt[N][K]   (tiled transpose, coalesced both sides)
// ---------------------------------------------------------------------------
__global__ __launch_bounds__(256) void convt_kernel(const float* __restrict__ W,
                                                    ushort* __restrict__ Wt,
                                                    int K, int N) {
  __shared__ float t[32][33];
  const int kb = blockIdx.x * 32, nb = blockIdx.y * 32;
  const int tx = threadIdx.x & 31, ty = threadIdx.x >> 5;
#pragma unroll
  for (int i = 0; i < 32; i += 8)
    t[ty + i][tx] = W[(size_t)(kb + ty + i) * N + (nb + tx)];
  __syncthreads();
#pragma unroll
  for (int i = 0; i < 32; i += 8)
    Wt[(size_t)(nb + ty + i) * K + (kb + tx)] = f2bf(t[tx][ty + i]);
}

// ---------------------------------------------------------------------------
// im2col: img (B,3,384,384) f32 -> Apatch (9216 x 768) bf16
// ---------------------------------------------------------------------------
__global__ __launch_bounds__(256) void im2col_kernel(const float* __restrict__ img,
                                                     ushort* __restrict__ Ap) {
  const int idx = blockIdx.x * 256 + threadIdx.x;  // 9216*768 exactly
  const int j = idx % 768;
  const int m = idx / 768;
  const int c = j % 3;
  const int q = j / 3;
  const int px = q & 15, py = q >> 4;
  const int b = m / 576, p = m % 576;
  const int gy = p / 24, gx = p % 24;
  const float v = img[((size_t)(b * 3 + c) * 384 + (gy * 16 + py)) * 384 + (gx * 16 + px)];
  Ap[idx] = f2bf(v);
}

__global__ void clspos_kernel(const float* __restrict__ cls_tok,
                              const float* __restrict__ pos,
                              float* __restrict__ x) {
  const int i = blockIdx.x * 256 + threadIdx.x;  // 16*768
  const int b = i / 768, d = i % 768;
  x[(size_t)b * NTOK * 768 + d] = cls_tok[d] + pos[d];
}

// ---------------------------------------------------------------------------
// LayerNorm row kernel: x f32 row (768) -> bf16 out row. 1 wave per row.
// ---------------------------------------------------------------------------
__global__ __launch_bounds__(64) void ln_kernel(const float* __restrict__ x,
                                                const float* __restrict__ w,
                                                const float* __restrict__ bb,
                                                ushort* __restrict__ out) {
  const int row = blockIdx.x, lane = threadIdx.x;
  const float4* xr = reinterpret_cast<const float4*>(x + (size_t)row * 768);
  const float4 v0 = xr[lane], v1 = xr[lane + 64], v2 = xr[lane + 128];
  float vals[12] = {v0.x, v0.y, v0.z, v0.w, v1.x, v1.y, v1.z, v1.w,
                    v2.x, v2.y, v2.z, v2.w};
  float s = 0.f;
#pragma unroll
  for (int i = 0; i < 12; ++i) s += vals[i];
#pragma unroll
  for (int o = 32; o; o >>= 1) s += __shfl_xor(s, o);
  const float mu = s * (1.0f / 768.0f);
  float q = 0.f;
#pragma unroll
  for (int i = 0; i < 12; ++i) { const float d = vals[i] - mu; q += d * d; }
#pragma unroll
  for (int o = 32; o; o >>= 1) q += __shfl_xor(q, o);
  const float rstd = rsqrtf(q * (1.0f / 768.0f) + 1e-5f);
  const float4* w4 = reinterpret_cast<const float4*>(w);
  const float4* b4 = reinterpret_cast<const float4*>(bb);
  ushort* orow = out + (size_t)row * 768;
#pragma unroll
  for (int ch = 0; ch < 3; ++ch) {
    const float4 wv = w4[lane + ch * 64];
    const float4 bv = b4[lane + ch * 64];
    ushort4 u;
    u.x = f2bf((vals[ch * 4 + 0] - mu) * rstd * wv.x + bv.x);
    u.y = f2bf((vals[ch * 4 + 1] - mu) * rstd * wv.y + bv.y);
    u.z = f2bf((vals[ch * 4 + 2] - mu) * rstd * wv.z + bv.z);
    u.w = f2bf((vals[ch * 4 + 3] - mu) * rstd * wv.w + bv.w);
    *reinterpret_cast<ushort4*>(orow + ch * 256 + lane * 4) = u;
  }
}

// ---------------------------------------------------------------------------
// Epilogue IDs
// ---------------------------------------------------------------------------
constexpr int EPI_BF16 = 0;       // C = acc                     -> bf16
constexpr int EPI_GELU_BF16 = 1;  // C = gelu(acc + bias)        -> bf16
constexpr int EPI_RES_F32 = 2;    // C = acc + bias + extra[r,c] -> f32
constexpr int EPI_PATCH = 3;      // x[row+b+1] = acc + patch_b + pos[p+1]

// ---------------------------------------------------------------------------
// 256x256 8-phase MFMA GEMM (T1+T2+T3+T4+T5). C(MxN) = A(MxK) @ Bt^T.
// 512 thr = 8 waves (2M x 4N), per-wave 128x64 out, BK=64, dbuf LDS 128KiB.
// Main loop (t < NT-1): stages next tile; vmcnt(4) at phases 0,1,2.
// Peeled last tile: no stages; drain vmcnt 4 -> 2 -> 0 (phases 0,1,2).
// LDS: [256 rows][64 k] bf16 per matrix; rotation swizzle on 16B granules.
// ---------------------------------------------------------------------------
template <int EPI>
__global__ __launch_bounds__(512, 2) void gemm8_kernel(
    const ushort* __restrict__ A, const ushort* __restrict__ Bt,
    const float* __restrict__ bias, void* __restrict__ Cptr,
    int M, int N, int K, int mt) {
  __shared__ ushort lds[2][2][16384];  // [buf][A/B][row*64 + phys]

  // T1: bijective XCD swizzle (m204)
  const int nwg = gridDim.x;
  const int orig = blockIdx.x;
  const int q8 = nwg >> 3, r8 = nwg & 7, xcd = orig & 7, sidx = orig >> 3;
  const int wg = (xcd < r8 ? xcd * (q8 + 1) : r8 * (q8 + 1) + (xcd - r8) * q8) + sidx;
  const int tileM = (wg % mt) * 256;
  const int tileN = (wg / mt) * 256;

  const int tid = threadIdx.x;
  const int wave = tid >> 6, lane = tid & 63;
  const int wm = wave >> 2, wn = wave & 3;
  const int lr = lane & 15, lg = lane >> 4;

  f32x4 acc[8][4];
#pragma unroll
  for (int i = 0; i < 8; ++i)
#pragma unroll
    for (int j = 0; j < 4; ++j) acc[i][j] = (f32x4){0.f, 0.f, 0.f, 0.f};

  // --- staging precompute (per-lane sources, wave-uniform LDS dests) ---
  int rsA[2][2], rsB[2][2];
  const ushort* pA[2][2];
  const ushort* pB[2][2];
#pragma unroll
  for (int h = 0; h < 2; ++h)
#pragma unroll
    for (int g = 0; g < 2; ++g) {
      const int c = wave * 2 + g;
      {
        const int rowst = h * 64 + ((c >> 3) << 7) + ((c & 7) << 3);
        rsA[h][g] = rowst;
        const int row = rowst + (lane >> 3);
        const int lgr = ((lane & 7) - gsw(row)) & 7;
        pA[h][g] = A + (size_t)(tileM + row) * K + lgr * 8;
      }
      {
        const int rowst = h * 32 + ((c >> 2) << 6) + ((c & 3) << 3);
        rsB[h][g] = rowst;
        const int row = rowst + (lane >> 3);
        const int lgr = ((lane & 7) - gsw(row)) & 7;
        pB[h][g] = Bt + (size_t)(tileN + row) * K + lgr * 8;
      }
    }

#define STAGE_A(h, buf, k1)                                   \
  gload_lds16(pA[h][0] + (k1), &lds[buf][0][rsA[h][0] * 64]); \
  gload_lds16(pA[h][1] + (k1), &lds[buf][0][rsA[h][1] * 64]);
#define STAGE_B(h, buf, k1)                                   \
  gload_lds16(pB[h][0] + (k1), &lds[buf][1][rsB[h][0] * 64]); \
  gload_lds16(pB[h][1] + (k1), &lds[buf][1][rsB[h][1] * 64]);

  bf16x8 areg[8], breg[4];
#define LDA8(h, buf)                                                          \
  {                                                                           \
    const ushort* base = &lds[buf][0][0];                                     \
    _Pragma("unroll") for (int mf = 0; mf < 4; ++mf) {                        \
      const int row = wm * 128 + (h) * 64 + mf * 16 + lr;                     \
      _Pragma("unroll") for (int ks = 0; ks < 2; ++ks) {                      \
        const int pg = (ks * 4 + lg + (lr & 7) + 2 * mf) & 7;                 \
        areg[mf * 2 + ks] =                                                   \
            *reinterpret_cast<const bf16x8*>(&base[row * 64 + pg * 8]);       \
      }                                                                       \
    }                                                                         \
  }
#define LDB4(q, buf)                                                          \
  {                                                                           \
    const ushort* base = &lds[buf][1][0];                                     \
    _Pragma("unroll") for (int nf = 0; nf < 2; ++nf) {                        \
      const int row = wn * 64 + (q) * 32 + nf * 16 + lr;                      \
      _Pragma("unroll") for (int ks = 0; ks < 2; ++ks) {                      \
        const int pg = (ks * 4 + lg + (lr & 7) + 2 * (((q)*2 + nf) & 3)) & 7; \
        breg[nf * 2 + ks] =                                                   \
            *reinterpret_cast<const bf16x8*>(&base[row * 64 + pg * 8]);       \
      }                                                                       \
    }                                                                         \
  }
#define MFMA16(h, q)                                                        \
  __builtin_amdgcn_s_setprio(1);                                            \
  _Pragma("unroll") for (int mf = 0; mf < 4; ++mf)                          \
      _Pragma("unroll") for (int nf = 0; nf < 2; ++nf)                      \
          _Pragma("unroll") for (int ks = 0; ks < 2; ++ks)                  \
              acc[(h)*4 + mf][(q)*2 + nf] =                                 \
                  __builtin_amdgcn_mfma_f32_16x16x32_bf16(                  \
                      areg[mf * 2 + ks], breg[nf * 2 + ks],                 \
                      acc[(h)*4 + mf][(q)*2 + nf], 0, 0, 0);                \
  __builtin_amdgcn_s_setprio(0);

  // --- prologue: stage K-tile 0 into buf 0, FIFO order A0,B0,A1,B1 ---
  STAGE_A(0, 0, 0);
  STAGE_B(0, 0, 0);
  STAGE_A(1, 0, 0);
  STAGE_B(1, 0, 0);

  const int NT = K >> 6;  // K-tiles of 64 (>= 2 here; K = 768 -> 12)
  for (int t = 0; t < NT - 1; ++t) {
    const int cb = t & 1, nb = (t + 1) & 1;
    const int k1 = (t + 1) * 64;
    // phase 0: quadrant (0,0); stage A0(t+1)
    VMCNT4; SCHED0;
    BARRIER;
    LDA8(0, cb);
    LDB4(0, cb);
    STAGE_A(0, nb, k1);
    LGKM0; SCHED0;
    MFMA16(0, 0);
    // phase 1: quadrant (1,0); stage B0(t+1)
    VMCNT4; SCHED0;
    BARRIER;
    LDA8(1, cb);
    STAGE_B(0, nb, k1);
    LGKM0; SCHED0;
    MFMA16(1, 0);
    // phase 2: quadrant (1,1); stage A1(t+1)
    VMCNT4; SCHED0;
    BARRIER;
    LDB4(1, cb);
    STAGE_A(1, nb, k1);
    LGKM0; SCHED0;
    MFMA16(1, 1);
    // phase 3: quadrant (0,1); stage B1(t+1)  (A0 re-read; already landed)
    BARRIER;
    LDA8(0, cb);
    STAGE_B(1, nb, k1);
    LGKM0; SCHED0;
    MFMA16(0, 1);
  }

  // --- peeled last K-tile: queue drains 8 -> 0; waits must drain too ---
  {
    const int cb = (NT - 1) & 1;
    VMCNT4; SCHED0;   // A0,B0 landed (8 -> 4)
    BARRIER;
    LDA8(0, cb);
    LDB4(0, cb);
    LGKM0; SCHED0;
    MFMA16(0, 0);
    VMCNT2; SCHED0;   // A1 landed (4 -> 2)
    BARRIER;
    LDA8(1, cb);
    LGKM0; SCHED0;
    MFMA16(1, 0);
    VMCNT0; SCHED0;   // B1 landed (2 -> 0)
    BARRIER;
    LDB4(1, cb);
    LGKM0; SCHED0;
    MFMA16(1, 1);
    BARRIER;
    LDA8(0, cb);
    LGKM0; SCHED0;
    MFMA16(0, 1);
  }

  // --- epilogue ---
#pragma unroll
  for (int am = 0; am < 8; ++am) {
#pragma unroll
    for (int r = 0; r < 4; ++r) {
      const int row = tileM + wm * 128 + (am >> 2) * 64 + (am & 3) * 16 + lg * 4 + r;
      if (row >= M) continue;
#pragma unroll
      for (int an = 0; an < 4; ++an) {
        const int col = tileN + wn * 64 + (an >> 1) * 32 + (an & 1) * 16 + lr;
        float v = acc[am][an][r];
        if constexpr (EPI == EPI_BF16) {
          reinterpret_cast<ushort*>(Cptr)[(size_t)row * N + col] = f2bf(v);
        } else {  // EPI_GELU_BF16
          v += bias[col];
          v = 0.5f * v * (1.0f + erff(v * 0.70710678118654752440f));
          reinterpret_cast<ushort*>(Cptr)[(size_t)row * N + col] = f2bf(v);
        }
      }
    }
  }
#undef STAGE_A
#undef STAGE_B
#undef LDA8
#undef LDB4
#undef MFMA16
}

// ---------------------------------------------------------------------------
// m97-structure MFMA GEMM (kept for proj / ff2 / patch, where N=768 makes
// 256^2 grids smaller than the CU count).
// ---------------------------------------------------------------------------
template <int EPI>
__global__ __launch_bounds__(256) void gemm_kernel(
    const ushort* __restrict__ A, const ushort* __restrict__ Bt,
    const float* __restrict__ bias, const float* __restrict__ extra,
    void* __restrict__ Cptr, int M, int N, int K) {
  __shared__ ushort Alds[128 * 32];
  __shared__ ushort Blds[128 * 32];
  const int tid = threadIdx.x;
  const int tileM = blockIdx.x * 128, tileN = blockIdx.y * 128;
  const int wave = tid >> 6, lane = tid & 63;
  const int wrow = (wave >> 1) * 64, wcol = (wave & 1) * 64;
  const int lr = lane & 15, lk = (lane >> 4) * 8;

  f32x4 acc[4][4];
#pragma unroll
  for (int m = 0; m < 4; ++m)
#pragma unroll
    for (int n = 0; n < 4; ++n) acc[m][n] = (f32x4){0.f, 0.f, 0.f, 0.f};

  const int srow = wave * 32 + (lane >> 2);
  const int scol = (lane & 3) * 8;
  const ushort* Ap = A + (size_t)(tileM + srow) * K + scol;
  const ushort* Bp = Bt + (size_t)(tileN + srow) * K + scol;
  ushort* Al0 = &Alds[(wave * 2 + 0) * 512];
  ushort* Al1 = &Alds[(wave * 2 + 1) * 512];
  ushort* Bl0 = &Blds[(wave * 2 + 0) * 512];
  ushort* Bl1 = &Blds[(wave * 2 + 1) * 512];
  const size_t cstride = (size_t)16 * K;

  for (int k0 = 0; k0 < K; k0 += 32) {
    __syncthreads();
    gload_lds16(Ap + k0, Al0);
    gload_lds16(Ap + k0 + cstride, Al1);
    gload_lds16(Bp + k0, Bl0);
    gload_lds16(Bp + k0 + cstride, Bl1);
    __syncthreads();

    bf16x8 af[4], bfr[4];
#pragma unroll
    for (int m = 0; m < 4; ++m)
      af[m] = *reinterpret_cast<const bf16x8*>(&Alds[(wrow + m * 16 + lr) * 32 + lk]);
#pragma unroll
    for (int n = 0; n < 4; ++n)
      bfr[n] = *reinterpret_cast<const bf16x8*>(&Blds[(wcol + n * 16 + lr) * 32 + lk]);
#pragma unroll
    for (int m = 0; m < 4; ++m)
#pragma unroll
      for (int n = 0; n < 4; ++n)
        acc[m][n] = __builtin_amdgcn_mfma_f32_16x16x32_bf16(af[m], bfr[n],
                                                            acc[m][n], 0, 0, 0);
  }

  const int lr4 = (lane >> 4) * 4;
#pragma unroll
  for (int m = 0; m < 4; ++m) {
#pragma unroll
    for (int r = 0; r < 4; ++r) {
      const int row = tileM + wrow + m * 16 + lr4 + r;
      if (row >= M) continue;
#pragma unroll
      for (int n = 0; n < 4; ++n) {
        const int col = tileN + wcol + n * 16 + lr;
        float v = acc[m][n][r];
        if constexpr (EPI == EPI_BF16) {
          reinterpret_cast<ushort*>(Cptr)[(size_t)row * N + col] = f2bf(v);
        } else if constexpr (EPI == EPI_GELU_BF16) {
          v += bias[col];
          v = 0.5f * v * (1.0f + erff(v * 0.70710678118654752440f));
          reinterpret_cast<ushort*>(Cptr)[(size_t)row * N + col] = f2bf(v);
        } else if constexpr (EPI == EPI_RES_F32) {
          v += bias[col] + extra[(size_t)row * N + col];
          reinterpret_cast<float*>(Cptr)[(size_t)row * N + col] = v;
        } else {  // EPI_PATCH
          const int bb = row / 576;
          const int p = row - bb * 576;
          v += bias[col] + extra[(size_t)(p + 1) * 768 + col];
          reinterpret_cast<float*>(Cptr)[(size_t)(row + bb + 1) * 768 + col] = v;
        }
      }
    }
  }
}

// ---------------------------------------------------------------------------
// MFMA flash attention with rotation-swizzled LDS.
// ---------------------------------------------------------------------------
__global__ __launch_bounds__(256) void attn_kernel(const ushort* __restrict__ qkv,
                                                   ushort* __restrict__ o) {
  __shared__ ushort sK[64 * 64];
  __shared__ ushort sVt[64 * 64];
  __shared__ ushort sP[4][16 * 72];
  const int bh = blockIdx.x;
  const int b = bh / 12, hh = bh % 12;
  const int q0 = blockIdx.y * 64;
  const int tid = threadIdx.x;
  const int wave = tid >> 6, lane = tid & 63;
  const int lr = lane & 15;
  const int lg = lane >> 4;
  const ushort* base = qkv + (size_t)b * NTOK * 2304 + hh * 64;
  const float SC = 0.03608439182435161f;  // 768^-0.5

  bf16x8 qf[2];
  {
    const int qrow = q0 + wave * 16 + lr;
    if (qrow < NTOK) {
      const ushort* qp = base + (size_t)qrow * 2304 + lg * 8;
      qf[0] = *reinterpret_cast<const bf16x8*>(qp);
      qf[1] = *reinterpret_cast<const bf16x8*>(qp + 32);
    } else {
      qf[0] = (bf16x8){0, 0, 0, 0, 0, 0, 0, 0};
      qf[1] = qf[0];
    }
  }

  float mst[4], lst[4];
  f32x4 oacc[4];
#pragma unroll
  for (int i = 0; i < 4; ++i) {
    mst[i] = -1e30f; lst[i] = 0.f;
    oacc[i] = (f32x4){0.f, 0.f, 0.f, 0.f};
  }

  const int skey = tid >> 2;      // 0..63
  const int sc4 = tid & 3;        // d-chunk: d = sc4*16 .. +15
  const int gswk = gsw(skey);

  for (int t0 = 0; t0 < NTOK; t0 += 64) {
    __syncthreads();
    {
      const int gk = t0 + skey;
      int4 k0v, k1v, v0v, v1v;
      if (gk < NTOK) {
        const int4* kp = reinterpret_cast<const int4*>(base + (size_t)gk * 2304 + 768 + sc4 * 16);
        k0v = kp[0]; k1v = kp[1];
        const int4* vp = reinterpret_cast<const int4*>(base + (size_t)gk * 2304 + 1536 + sc4 * 16);
        v0v = vp[0]; v1v = vp[1];
      } else {
        int4 z; z.x = z.y = z.z = z.w = 0;
        k0v = k1v = v0v = v1v = z;
      }
      *reinterpret_cast<int4*>(&sK[skey * 64 + (((2 * sc4 + 0) + gswk) & 7) * 8]) = k0v;
      *reinterpret_cast<int4*>(&sK[skey * 64 + (((2 * sc4 + 1) + gswk) & 7) * 8]) = k1v;
      const ushort* vs = reinterpret_cast<const ushort*>(&v0v);
      const ushort* vs2 = reinterpret_cast<const ushort*>(&v1v);
#pragma unroll
      for (int i = 0; i < 8; ++i) {
        const int d0 = sc4 * 16 + i;
        const int pg0 = ((skey >> 3) + gsw(d0)) & 7;
        sVt[d0 * 64 + pg0 * 8 + (skey & 7)] = vs[i];
        const int d1 = sc4 * 16 + 8 + i;
        const int pg1 = ((skey >> 3) + gsw(d1)) & 7;
        sVt[d1 * 64 + pg1 * 8 + (skey & 7)] = vs2[i];
      }
    }
    __syncthreads();

    // ---- S = Q K^T ----
    f32x4 sacc[4];
#pragma unroll
    for (int n = 0; n < 4; ++n) sacc[n] = (f32x4){0.f, 0.f, 0.f, 0.f};
#pragma unroll
    for (int n = 0; n < 4; ++n) {
      const int row = n * 16 + lr;
      const int rot = (lr & 7) + 2 * n;  // gsw(row) for row<64
      const bf16x8 kf0 = *reinterpret_cast<const bf16x8*>(&sK[row * 64 + ((lg + rot) & 7) * 8]);
      const bf16x8 kf1 = *reinterpret_cast<const bf16x8*>(&sK[row * 64 + ((4 + lg + rot) & 7) * 8]);
      sacc[n] = __builtin_amdgcn_mfma_f32_16x16x32_bf16(qf[0], kf0, sacc[n], 0, 0, 0);
      sacc[n] = __builtin_amdgcn_mfma_f32_16x16x32_bf16(qf[1], kf1, sacc[n], 0, 0, 0);
    }

    // ---- online softmax ----
    float s[4][4], pm[4];
#pragma unroll
    for (int reg = 0; reg < 4; ++reg) pm[reg] = -1e30f;
#pragma unroll
    for (int n = 0; n < 4; ++n)
#pragma unroll
      for (int reg = 0; reg < 4; ++reg) {
        float v = sacc[n][reg] * SC;
        if (t0 + n * 16 + lr >= NTOK) v = -1e30f;
        s[n][reg] = v;
        pm[reg] = fmaxf(pm[reg], v);
      }
#pragma unroll
    for (int off = 1; off < 16; off <<= 1)
#pragma unroll
      for (int reg = 0; reg < 4; ++reg) pm[reg] = fmaxf(pm[reg], __shfl_xor(pm[reg], off));

    float al[4], rs[4];
#pragma unroll
    for (int reg = 0; reg < 4; ++reg) {
      const float mn = fmaxf(mst[reg], pm[reg]);
      al[reg] = __expf(mst[reg] - mn);
      mst[reg] = mn;
      rs[reg] = 0.f;
    }
#pragma unroll
    for (int n = 0; n < 4; ++n)
#pragma unroll
      for (int reg = 0; reg < 4; ++reg) {
        s[n][reg] = __expf(s[n][reg] - mst[reg]);
        rs[reg] += s[n][reg];
      }
#pragma unroll
    for (int off = 1; off < 16; off <<= 1)
#pragma unroll
      for (int reg = 0; reg < 4; ++reg) rs[reg] += __shfl_xor(rs[reg], off);
#pragma unroll
    for (int reg = 0; reg < 4; ++reg) {
      lst[reg] = lst[reg] * al[reg] + rs[reg];
#pragma unroll
      for (int n = 0; n < 4; ++n) oacc[n][reg] *= al[reg];
    }

    // ---- P -> per-wave LDS ----
#pragma unroll
    for (int n = 0; n < 4; ++n)
#pragma unroll
      for (int reg = 0; reg < 4; ++reg)
        sP[wave][(lg * 4 + reg) * 72 + n * 16 + lr] = f2bf(s[n][reg]);

    // ---- O += P V ----
    const bf16x8 pf0 = *reinterpret_cast<const bf16x8*>(&sP[wave][lr * 72 + lg * 8]);
    const bf16x8 pf1 = *reinterpret_cast<const bf16x8*>(&sP[wave][lr * 72 + 32 + lg * 8]);
#pragma unroll
    for (int n = 0; n < 4; ++n) {
      const int row = n * 16 + lr;
      const int rot = (lr & 7) + 2 * n;
      const bf16x8 vf0 = *reinterpret_cast<const bf16x8*>(&sVt[row * 64 + ((lg + rot) & 7) * 8]);
      const bf16x8 vf1 = *reinterpret_cast<const bf16x8*>(&sVt[row * 64 + ((4 + lg + rot) & 7) * 8]);
      oacc[n] = __builtin_amdgcn_mfma_f32_16x16x32_bf16(pf0, vf0, oacc[n], 0, 0, 0);
      oacc[n] = __builtin_amdgcn_mfma_f32_16x16x32_bf16(pf1, vf1, oacc[n], 0, 0, 0);
    }
  }

#pragma unroll
  for (int reg = 0; reg < 4; ++reg) {
    const int q = q0 + wave * 16 + lg * 4 + reg;
    if (q >= NTOK) continue;
    const float inv = 1.0f / lst[reg];
    ushort* op = o + (size_t)(b * NTOK + q) * 768 + hh * 64;
#pragma unroll
    for (int n = 0; n < 4; ++n) op[n * 16 + lr] = f2bf(oacc[n][reg] * inv);
  }
}

// ---------------------------------------------------------------------------
// Head: LN(cls rows) @ head_w (768x1000) + head_b -> out (16x1000) f32
// ---------------------------------------------------------------------------
__global__ __launch_bounds__(256) void head_kernel(const float* __restrict__ x,
                                                   const float* __restrict__ lw,
                                                   const float* __restrict__ lb,
                                                   const float* __restrict__ hw,
                                                   const float* __restrict__ hb,
                                                   float* __restrict__ out) {
  __shared__ float srow[768];
  __shared__ float sred[8];
  const int b = blockIdx.x, tid = threadIdx.x;
  const float* xr = x + (size_t)b * NTOK * 768;
  for (int i = tid; i < 768; i += 256) srow[i] = xr[i];
  __syncthreads();
  float part = srow[tid] + srow[tid + 256] + srow[tid + 512];
#pragma unroll
  for (int off = 32; off; off >>= 1) part += __shfl_xor(part, off);
  if ((tid & 63) == 0) sred[tid >> 6] = part;
  __syncthreads();
  const float mu = (sred[0] + sred[1] + sred[2] + sred[3]) * (1.0f / 768.0f);
  const float d0 = srow[tid] - mu, d1 = srow[tid + 256] - mu, d2 = srow[tid + 512] - mu;
  float vp = d0 * d0 + d1 * d1 + d2 * d2;
#pragma unroll
  for (int off = 32; off; off >>= 1) vp += __shfl_xor(vp, off);
  if ((tid & 63) == 0) sred[4 + (tid >> 6)] = vp;
  __syncthreads();
  const float rstd = rsqrtf((sred[4] + sred[5] + sred[6] + sred[7]) * (1.0f / 768.0f) + 1e-5f);
  for (int i = tid; i < 768; i += 256) srow[i] = (srow[i] - mu) * rstd * lw[i] + lb[i];
  __syncthreads();
  const int c = blockIdx.y * 250 + tid;
  if (tid < 250 && c < 1000) {
    float a = 0.f;
#pragma unroll 4
    for (int k = 0; k < 768; ++k) a += srow[k] * hw[(size_t)k * 1000 + c];
    out[b * 1000 + c] = a + hb[c];
  }
}

// ---------------------------------------------------------------------------
extern "C" void kernel_launch(void* const* d_in, const int* in_sizes, int n_in,
                              void* d_out, int out_size, void* d_ws, size_t ws_size,
                              hipStream_t stream) {
  const float* img     = (const float*)d_in[0];
  const float* patch_w = (const float*)d_in[1];
  const float* patch_b = (const float*)d_in[2];
  const float* pos_emb = (const float*)d_in[3];
  const float* cls_tok = (const float*)d_in[4];
  const float* ln1_w   = (const float*)d_in[5];
  const float* ln1_b   = (const float*)d_in[6];
  const float* qkv_w   = (const float*)d_in[7];
  const float* out_w   = (const float*)d_in[8];
  const float* out_b   = (const float*)d_in[9];
  const float* ln2_w   = (const float*)d_in[10];
  const float* ln2_b   = (const float*)d_in[11];
  const float* ff1_w   = (const float*)d_in[12];
  const float* ff1_b   = (const float*)d_in[13];
  const float* ff2_w   = (const float*)d_in[14];
  const float* ff2_b   = (const float*)d_in[15];
  const float* hln_w   = (const float*)d_in[16];
  const float* hln_b   = (const float*)d_in[17];
  const float* head_w  = (const float*)d_in[18];
  const float* head_b  = (const float*)d_in[19];
  float* outp = (float*)d_out;

  char* wsp = (char*)d_ws;
  auto alloc = [&](size_t bytes) {
    char* p = wsp;
    wsp += (bytes + 255) & ~(size_t)255;
    return p;
  };
  float*  x    = (float*) alloc((size_t)9232 * 768 * 4);
  ushort* h    = (ushort*)alloc((size_t)9232 * 768 * 2);
  ushort* qkvb = (ushort*)alloc((size_t)9232 * 2304 * 2);
  ushort* mlp  = (ushort*)alloc((size_t)9232 * 3072 * 2);
  ushort* wq   = (ushort*)alloc((size_t)768 * 2304 * 2);
  ushort* wo   = (ushort*)alloc((size_t)768 * 768 * 2);
  ushort* w1   = (ushort*)alloc((size_t)768 * 3072 * 2);
  ushort* w2   = (ushort*)alloc((size_t)3072 * 768 * 2);
  ushort* apatch = mlp;
  ushort* wpatch = wq;

  // ---- patch embedding ----
  convt_kernel<<<dim3(24, 24), 256, 0, stream>>>(patch_w, wpatch, 768, 768);
  im2col_kernel<<<27648, 256, 0, stream>>>(img, apatch);
  gemm_kernel<EPI_PATCH><<<dim3(72, 6), 256, 0, stream>>>(
      apatch, wpatch, patch_b, pos_emb, x, 9216, 768, 768);
  clspos_kernel<<<48, 256, 0, stream>>>(cls_tok, pos_emb, x);

  // ---- transformer layers ----
  for (int l = 0; l < 12; ++l) {
    ln_kernel<<<9232, 64, 0, stream>>>(x, ln1_w + l * 768, ln1_b + l * 768, h);
    convt_kernel<<<dim3(24, 72), 256, 0, stream>>>(qkv_w + (size_t)l * 768 * 2304, wq, 768, 2304);
    gemm8_kernel<EPI_BF16><<<37 * 9, 512, 0, stream>>>(
        h, wq, nullptr, qkvb, 9232, 2304, 768, 37);
    attn_kernel<<<dim3(192, 10), 256, 0, stream>>>(qkvb, h);  // o -> h
    convt_kernel<<<dim3(24, 24), 256, 0, stream>>>(out_w + (size_t)l * 768 * 768, wo, 768, 768);
    gemm_kernel<EPI_RES_F32><<<dim3(73, 6), 256, 0, stream>>>(
        h, wo, out_b + l * 768, x, x, 9232, 768, 768);
    ln_kernel<<<9232, 64, 0, stream>>>(x, ln2_w + l * 768, ln2_b + l * 768, h);
    convt_kernel<<<dim3(24, 96), 256, 0, stream>>>(ff1_w + (size_t)l * 768 * 3072, w1, 768, 3072);
    gemm8_kernel<EPI_GELU_BF16><<<37 * 12, 512, 0, stream>>>(
        h, w1, ff1_b + l * 3072, mlp, 9232, 3072, 768, 37);
    convt_kernel<<<dim3(96, 24), 256, 0, stream>>>(ff2_w + (size_t)l * 3072 * 768, w2, 3072, 768);
    gemm_kernel<EPI_RES_F32><<<dim3(73, 6), 256, 0, stream>>>(
        mlp, w2, ff2_b + l * 768, x, x, 9232, 768, 3072);
  }

  // ---- classification head ----
  head_kernel<<<dim3(16, 4), 256, 0, stream>>>(x, hln_w, hln_b, head_w, head_b, outp);
}

// Round 6
// 4280.132 us; speedup vs baseline: 2.2844x; 1.0837x over previous
//
#include <hip/hip_runtime.h>
#include <cstdint>

// ============================================================================
// ViT forward, MI355X round 5.
//   R5 change vs R4: new gemmP_kernel (128x128, BK=64, dbuf LDS 64 KiB ->
//   2 blocks/CU, stage-early "minimum 2-phase": one vmcnt(0)+barrier per
//   K-tile, 32 MFMA/wave/tile) replaces the m97 gemm_kernel for
//   patch / proj / ff2. Grids 432/438 blocks are fully resident (no rounds);
//   cross-block overlap hides stage latency (m114 mechanism).
//   qkv/ff1 stay on gemm8 (256^2 counted-vmcnt) as in-run control.
// ============================================================================

typedef __attribute__((ext_vector_type(8))) short bf16x8;
typedef __attribute__((ext_vector_type(4))) float f32x4;

#define NTOK 577

__device__ __forceinline__ ushort f2bf(float f) {
  union { float f; unsigned int u; } x; x.f = f;
  unsigned int r = x.u + 0x7fffu + ((x.u >> 16) & 1u);  // RNE
  return (ushort)(r >> 16);
}

__device__ __forceinline__ void gload_lds16(const ushort* g, ushort* l) {
  __builtin_amdgcn_global_load_lds(
      (const __attribute__((address_space(1))) unsigned int*)g,
      (__attribute__((address_space(3))) unsigned int*)l, 16, 0, 0);
}

#define VMCNT4 asm volatile("s_waitcnt vmcnt(4)" ::: "memory")
#define VMCNT2 asm volatile("s_waitcnt vmcnt(2)" ::: "memory")
#define VMCNT0 asm volatile("s_waitcnt vmcnt(0)" ::: "memory")
#define LGKM0  asm volatile("s_waitcnt lgkmcnt(0)" ::: "memory")
#define SCHED0 __builtin_amdgcn_sched_barrier(0)
#define BARRIER __builtin_amdgcn_s_barrier()

// rotation swizzle: logical 16B-granule at row -> physical granule rotation
__device__ __forceinline__ int gsw(int row) {
  return (row & 7) + 2 * ((row >> 4) & 3);
}

// ---------------------------------------------------------------------------
// f32 W[K][N]  ->  bf16 Wt[N][K]   (tiled transpose, coalesced both sides)
// ---------------------------------------------------------------------------
__global__ __launch_bounds__(256) void convt_kernel(const float* __restrict__ W,
                                                    ushort* __restrict__ Wt,
                                                    int K, int N) {
  __shared__ float t[32][33];
  const int kb = blockIdx.x * 32, nb = blockIdx.y * 32;
  const int tx = threadIdx.x & 31, ty = threadIdx.x >> 5;
#pragma unroll
  for (int i = 0; i < 32; i += 8)
    t[ty + i][tx] = W[(size_t)(kb + ty + i) * N + (nb + tx)];
  __syncthreads();
#pragma unroll
  for (int i = 0; i < 32; i += 8)
    Wt[(size_t)(nb + ty + i) * K + (kb + tx)] = f2bf(t[tx][ty + i]);
}

// ---------------------------------------------------------------------------
// im2col: img (B,3,384,384) f32 -> Apatch (9216 x 768) bf16
// ---------------------------------------------------------------------------
__global__ __launch_bounds__(256) void im2col_kernel(const float* __restrict__ img,
                                                     ushort* __restrict__ Ap) {
  const int idx = blockIdx.x * 256 + threadIdx.x;  // 9216*768 exactly
  const int j = idx % 768;
  const int m = idx / 768;
  const int c = j % 3;
  const int q = j / 3;
  const int px = q & 15, py = q >> 4;
  const int b = m / 576, p = m % 576;
  const int gy = p / 24, gx = p % 24;
  const float v = img[((size_t)(b * 3 + c) * 384 + (gy * 16 + py)) * 384 + (gx * 16 + px)];
  Ap[idx] = f2bf(v);
}

__global__ void clspos_kernel(const float* __restrict__ cls_tok,
                              const float* __restrict__ pos,
                              float* __restrict__ x) {
  const int i = blockIdx.x * 256 + threadIdx.x;  // 16*768
  const int b = i / 768, d = i % 768;
  x[(size_t)b * NTOK * 768 + d] = cls_tok[d] + pos[d];
}

// ---------------------------------------------------------------------------
// LayerNorm row kernel: x f32 row (768) -> bf16 out row. 1 wave per row.
// ---------------------------------------------------------------------------
__global__ __launch_bounds__(64) void ln_kernel(const float* __restrict__ x,
                                                const float* __restrict__ w,
                                                const float* __restrict__ bb,
                                                ushort* __restrict__ out) {
  const int row = blockIdx.x, lane = threadIdx.x;
  const float4* xr = reinterpret_cast<const float4*>(x + (size_t)row * 768);
  const float4 v0 = xr[lane], v1 = xr[lane + 64], v2 = xr[lane + 128];
  float vals[12] = {v0.x, v0.y, v0.z, v0.w, v1.x, v1.y, v1.z, v1.w,
                    v2.x, v2.y, v2.z, v2.w};
  float s = 0.f;
#pragma unroll
  for (int i = 0; i < 12; ++i) s += vals[i];
#pragma unroll
  for (int o = 32; o; o >>= 1) s += __shfl_xor(s, o);
  const float mu = s * (1.0f / 768.0f);
  float q = 0.f;
#pragma unroll
  for (int i = 0; i < 12; ++i) { const float d = vals[i] - mu; q += d * d; }
#pragma unroll
  for (int o = 32; o; o >>= 1) q += __shfl_xor(q, o);
  const float rstd = rsqrtf(q * (1.0f / 768.0f) + 1e-5f);
  const float4* w4 = reinterpret_cast<const float4*>(w);
  const float4* b4 = reinterpret_cast<const float4*>(bb);
  ushort* orow = out + (size_t)row * 768;
#pragma unroll
  for (int ch = 0; ch < 3; ++ch) {
    const float4 wv = w4[lane + ch * 64];
    const float4 bv = b4[lane + ch * 64];
    ushort4 u;
    u.x = f2bf((vals[ch * 4 + 0] - mu) * rstd * wv.x + bv.x);
    u.y = f2bf((vals[ch * 4 + 1] - mu) * rstd * wv.y + bv.y);
    u.z = f2bf((vals[ch * 4 + 2] - mu) * rstd * wv.z + bv.z);
    u.w = f2bf((vals[ch * 4 + 3] - mu) * rstd * wv.w + bv.w);
    *reinterpret_cast<ushort4*>(orow + ch * 256 + lane * 4) = u;
  }
}

// ---------------------------------------------------------------------------
// Epilogue IDs
// ---------------------------------------------------------------------------
constexpr int EPI_BF16 = 0;       // C = acc                     -> bf16
constexpr int EPI_GELU_BF16 = 1;  // C = gelu(acc + bias)        -> bf16
constexpr int EPI_RES_F32 = 2;    // C = acc + bias + extra[r,c] -> f32
constexpr int EPI_PATCH = 3;      // x[row+b+1] = acc + patch_b + pos[p+1]

// ---------------------------------------------------------------------------
// 256x256 8-phase MFMA GEMM (qkv / ff1). Unchanged from R4.
// ---------------------------------------------------------------------------
template <int EPI>
__global__ __launch_bounds__(512, 2) void gemm8_kernel(
    const ushort* __restrict__ A, const ushort* __restrict__ Bt,
    const float* __restrict__ bias, void* __restrict__ Cptr,
    int M, int N, int K, int mt) {
  __shared__ ushort lds[2][2][16384];  // [buf][A/B][row*64 + phys]

  const int nwg = gridDim.x;
  const int orig = blockIdx.x;
  const int q8 = nwg >> 3, r8 = nwg & 7, xcd = orig & 7, sidx = orig >> 3;
  const int wg = (xcd < r8 ? xcd * (q8 + 1) : r8 * (q8 + 1) + (xcd - r8) * q8) + sidx;
  const int tileM = (wg % mt) * 256;
  const int tileN = (wg / mt) * 256;

  const int tid = threadIdx.x;
  const int wave = tid >> 6, lane = tid & 63;
  const int wm = wave >> 2, wn = wave & 3;
  const int lr = lane & 15, lg = lane >> 4;

  f32x4 acc[8][4];
#pragma unroll
  for (int i = 0; i < 8; ++i)
#pragma unroll
    for (int j = 0; j < 4; ++j) acc[i][j] = (f32x4){0.f, 0.f, 0.f, 0.f};

  int rsA[2][2], rsB[2][2];
  const ushort* pA[2][2];
  const ushort* pB[2][2];
#pragma unroll
  for (int h = 0; h < 2; ++h)
#pragma unroll
    for (int g = 0; g < 2; ++g) {
      const int c = wave * 2 + g;
      {
        const int rowst = h * 64 + ((c >> 3) << 7) + ((c & 7) << 3);
        rsA[h][g] = rowst;
        const int row = rowst + (lane >> 3);
        const int lgr = ((lane & 7) - gsw(row)) & 7;
        pA[h][g] = A + (size_t)(tileM + row) * K + lgr * 8;
      }
      {
        const int rowst = h * 32 + ((c >> 2) << 6) + ((c & 3) << 3);
        rsB[h][g] = rowst;
        const int row = rowst + (lane >> 3);
        const int lgr = ((lane & 7) - gsw(row)) & 7;
        pB[h][g] = Bt + (size_t)(tileN + row) * K + lgr * 8;
      }
    }

#define STAGE_A(h, buf, k1)                                   \
  gload_lds16(pA[h][0] + (k1), &lds[buf][0][rsA[h][0] * 64]); \
  gload_lds16(pA[h][1] + (k1), &lds[buf][0][rsA[h][1] * 64]);
#define STAGE_B(h, buf, k1)                                   \
  gload_lds16(pB[h][0] + (k1), &lds[buf][1][rsB[h][0] * 64]); \
  gload_lds16(pB[h][1] + (k1), &lds[buf][1][rsB[h][1] * 64]);

  bf16x8 areg[8], breg[4];
#define LDA8(h, buf)                                                          \
  {                                                                           \
    const ushort* base = &lds[buf][0][0];                                     \
    _Pragma("unroll") for (int mf = 0; mf < 4; ++mf) {                        \
      const int row = wm * 128 + (h) * 64 + mf * 16 + lr;                     \
      _Pragma("unroll") for (int ks = 0; ks < 2; ++ks) {                      \
        const int pg = (ks * 4 + lg + (lr & 7) + 2 * mf) & 7;                 \
        areg[mf * 2 + ks] =                                                   \
            *reinterpret_cast<const bf16x8*>(&base[row * 64 + pg * 8]);       \
      }                                                                       \
    }                                                                         \
  }
#define LDB4(q, buf)                                                          \
  {                                                                           \
    const ushort* base = &lds[buf][1][0];                                     \
    _Pragma("unroll") for (int nf = 0; nf < 2; ++nf) {                        \
      const int row = wn * 64 + (q) * 32 + nf * 16 + lr;                      \
      _Pragma("unroll") for (int ks = 0; ks < 2; ++ks) {                      \
        const int pg = (ks * 4 + lg + (lr & 7) + 2 * (((q)*2 + nf) & 3)) & 7; \
        breg[nf * 2 + ks] =                                                   \
            *reinterpret_cast<const bf16x8*>(&base[row * 64 + pg * 8]);       \
      }                                                                       \
    }                                                                         \
  }
#define MFMA16(h, q)                                                        \
  __builtin_amdgcn_s_setprio(1);                                            \
  _Pragma("unroll") for (int mf = 0; mf < 4; ++mf)                          \
      _Pragma("unroll") for (int nf = 0; nf < 2; ++nf)                      \
          _Pragma("unroll") for (int ks = 0; ks < 2; ++ks)                  \
              acc[(h)*4 + mf][(q)*2 + nf] =                                 \
                  __builtin_amdgcn_mfma_f32_16x16x32_bf16(                  \
                      areg[mf * 2 + ks], breg[nf * 2 + ks],                 \
                      acc[(h)*4 + mf][(q)*2 + nf], 0, 0, 0);                \
  __builtin_amdgcn_s_setprio(0);

  STAGE_A(0, 0, 0);
  STAGE_B(0, 0, 0);
  STAGE_A(1, 0, 0);
  STAGE_B(1, 0, 0);

  const int NT = K >> 6;
  for (int t = 0; t < NT - 1; ++t) {
    const int cb = t & 1, nb = (t + 1) & 1;
    const int k1 = (t + 1) * 64;
    VMCNT4; SCHED0;
    BARRIER;
    LDA8(0, cb);
    LDB4(0, cb);
    STAGE_A(0, nb, k1);
    LGKM0; SCHED0;
    MFMA16(0, 0);
    VMCNT4; SCHED0;
    BARRIER;
    LDA8(1, cb);
    STAGE_B(0, nb, k1);
    LGKM0; SCHED0;
    MFMA16(1, 0);
    VMCNT4; SCHED0;
    BARRIER;
    LDB4(1, cb);
    STAGE_A(1, nb, k1);
    LGKM0; SCHED0;
    MFMA16(1, 1);
    BARRIER;
    LDA8(0, cb);
    STAGE_B(1, nb, k1);
    LGKM0; SCHED0;
    MFMA16(0, 1);
  }

  {  // peeled last K-tile with drain waits
    const int cb = (NT - 1) & 1;
    VMCNT4; SCHED0;
    BARRIER;
    LDA8(0, cb);
    LDB4(0, cb);
    LGKM0; SCHED0;
    MFMA16(0, 0);
    VMCNT2; SCHED0;
    BARRIER;
    LDA8(1, cb);
    LGKM0; SCHED0;
    MFMA16(1, 0);
    VMCNT0; SCHED0;
    BARRIER;
    LDB4(1, cb);
    LGKM0; SCHED0;
    MFMA16(1, 1);
    BARRIER;
    LDA8(0, cb);
    LGKM0; SCHED0;
    MFMA16(0, 1);
  }

#pragma unroll
  for (int am = 0; am < 8; ++am) {
#pragma unroll
    for (int r = 0; r < 4; ++r) {
      const int row = tileM + wm * 128 + (am >> 2) * 64 + (am & 3) * 16 + lg * 4 + r;
      if (row >= M) continue;
#pragma unroll
      for (int an = 0; an < 4; ++an) {
        const int col = tileN + wn * 64 + (an >> 1) * 32 + (an & 1) * 16 + lr;
        float v = acc[am][an][r];
        if constexpr (EPI == EPI_BF16) {
          reinterpret_cast<ushort*>(Cptr)[(size_t)row * N + col] = f2bf(v);
        } else {  // EPI_GELU_BF16
          v += bias[col];
          v = 0.5f * v * (1.0f + erff(v * 0.70710678118654752440f));
          reinterpret_cast<ushort*>(Cptr)[(size_t)row * N + col] = f2bf(v);
        }
      }
    }
  }
#undef STAGE_A
#undef STAGE_B
#undef LDA8
#undef LDB4
#undef MFMA16
}

// ---------------------------------------------------------------------------
// gemmP: 128x128 tile, BK=64, dbuf LDS 64 KiB (2 blocks/CU), 256 thr =
// 4 waves (2M x 2N, per-wave 64x64). Per K-tile: one vmcnt(0)+barrier,
// stage-all of tile t+1 issued right after the barrier (full-tile
// issue->consume distance), 16 ds_read_b128, 32 MFMA under setprio.
// Rotation swizzle on 16B granules (pre-swizzled global source + swizzled
// ds_read, rule #21). Used for patch / proj / ff2.
// ---------------------------------------------------------------------------
template <int EPI>
__global__ __launch_bounds__(256) void gemmP_kernel(
    const ushort* __restrict__ A, const ushort* __restrict__ Bt,
    const float* __restrict__ bias, const float* __restrict__ extra,
    void* __restrict__ Cptr, int M, int N, int K, int mt) {
  __shared__ ushort ldsA[2][128 * 64];
  __shared__ ushort ldsB[2][128 * 64];

  // bijective XCD swizzle (m204)
  const int nwg = gridDim.x;
  const int orig = blockIdx.x;
  const int q8 = nwg >> 3, r8 = nwg & 7, xcd = orig & 7, sidx = orig >> 3;
  const int wg = (xcd < r8 ? xcd * (q8 + 1) : r8 * (q8 + 1) + (xcd - r8) * q8) + sidx;
  const int tileM = (wg % mt) * 128;
  const int tileN = (wg / mt) * 128;

  const int tid = threadIdx.x;
  const int wave = tid >> 6, lane = tid & 63;
  const int wm = wave >> 1, wn = wave & 1;
  const int lr = lane & 15, lg = lane >> 4;

  f32x4 acc[4][4];
#pragma unroll
  for (int m = 0; m < 4; ++m)
#pragma unroll
    for (int n = 0; n < 4; ++n) acc[m][n] = (f32x4){0.f, 0.f, 0.f, 0.f};

  // staging: 16 A-chunks + 16 B-chunks of 8 rows (1 KiB each); wave w owns
  // chunks 4w..4w+3 of each. Per-lane source pre-swizzled by gsw(row).
  const ushort* pA[4];
  const ushort* pB[4];
  int dst[4];
#pragma unroll
  for (int i = 0; i < 4; ++i) {
    const int c = wave * 4 + i;
    const int rowst = c * 8;
    dst[i] = rowst * 64;
    const int row = rowst + (lane >> 3);
    const int lgr = ((lane & 7) - gsw(row)) & 7;
    pA[i] = A + (size_t)(tileM + row) * K + lgr * 8;
    pB[i] = Bt + (size_t)(tileN + row) * K + lgr * 8;
  }

#define PSTAGE(buf, kk)                              \
  _Pragma("unroll") for (int i = 0; i < 4; ++i)      \
      gload_lds16(pA[i] + (kk), &ldsA[buf][dst[i]]); \
  _Pragma("unroll") for (int i = 0; i < 4; ++i)      \
      gload_lds16(pB[i] + (kk), &ldsB[buf][dst[i]]);

  PSTAGE(0, 0);

  const int NT = K >> 6;
  int cb = 0;
  for (int t = 0; t < NT; ++t) {
    VMCNT0; SCHED0;   // own loads of tile t landed
    BARRIER;          // all waves' loads landed
    if (t + 1 < NT) { PSTAGE(cb ^ 1, (t + 1) * 64); }
    bf16x8 a[8], b[8];
#pragma unroll
    for (int mf = 0; mf < 4; ++mf) {
      const int row = wm * 64 + mf * 16 + lr;
#pragma unroll
      for (int ks = 0; ks < 2; ++ks) {
        const int pg = (ks * 4 + lg + (lr & 7) + 2 * mf) & 7;
        a[mf * 2 + ks] = *reinterpret_cast<const bf16x8*>(&ldsA[cb][row * 64 + pg * 8]);
      }
    }
#pragma unroll
    for (int nf = 0; nf < 4; ++nf) {
      const int row = wn * 64 + nf * 16 + lr;
#pragma unroll
      for (int ks = 0; ks < 2; ++ks) {
        const int pg = (ks * 4 + lg + (lr & 7) + 2 * nf) & 7;
        b[nf * 2 + ks] = *reinterpret_cast<const bf16x8*>(&ldsB[cb][row * 64 + pg * 8]);
      }
    }
    LGKM0; SCHED0;
    __builtin_amdgcn_s_setprio(1);
#pragma unroll
    for (int mf = 0; mf < 4; ++mf)
#pragma unroll
      for (int nf = 0; nf < 4; ++nf)
#pragma unroll
        for (int ks = 0; ks < 2; ++ks)
          acc[mf][nf] = __builtin_amdgcn_mfma_f32_16x16x32_bf16(
              a[mf * 2 + ks], b[nf * 2 + ks], acc[mf][nf], 0, 0, 0);
    __builtin_amdgcn_s_setprio(0);
    cb ^= 1;
  }

  // epilogue: row = tileM + wm*64 + mf*16 + lg*4 + r ; col = tileN + wn*64 + nf*16 + lr
#pragma unroll
  for (int mf = 0; mf < 4; ++mf) {
#pragma unroll
    for (int r = 0; r < 4; ++r) {
      const int row = tileM + wm * 64 + mf * 16 + lg * 4 + r;
      if (row >= M) continue;
#pragma unroll
      for (int nf = 0; nf < 4; ++nf) {
        const int col = tileN + wn * 64 + nf * 16 + lr;
        float v = acc[mf][nf][r];
        if constexpr (EPI == EPI_BF16) {
          reinterpret_cast<ushort*>(Cptr)[(size_t)row * N + col] = f2bf(v);
        } else if constexpr (EPI == EPI_GELU_BF16) {
          v += bias[col];
          v = 0.5f * v * (1.0f + erff(v * 0.70710678118654752440f));
          reinterpret_cast<ushort*>(Cptr)[(size_t)row * N + col] = f2bf(v);
        } else if constexpr (EPI == EPI_RES_F32) {
          v += bias[col] + extra[(size_t)row * N + col];
          reinterpret_cast<float*>(Cptr)[(size_t)row * N + col] = v;
        } else {  // EPI_PATCH: row = b*576+p -> x row b*577+1+p
          const int bb = row / 576;
          const int p = row - bb * 576;
          v += bias[col] + extra[(size_t)(p + 1) * 768 + col];
          reinterpret_cast<float*>(Cptr)[(size_t)(row + bb + 1) * 768 + col] = v;
        }
      }
    }
  }
#undef PSTAGE
}

// ---------------------------------------------------------------------------
// MFMA flash attention with rotation-swizzled LDS. Unchanged from R4.
// ---------------------------------------------------------------------------
__global__ __launch_bounds__(256) void attn_kernel(const ushort* __restrict__ qkv,
                                                   ushort* __restrict__ o) {
  __shared__ ushort sK[64 * 64];
  __shared__ ushort sVt[64 * 64];
  __shared__ ushort sP[4][16 * 72];
  const int bh = blockIdx.x;
  const int b = bh / 12, hh = bh % 12;
  const int q0 = blockIdx.y * 64;
  const int tid = threadIdx.x;
  const int wave = tid >> 6, lane = tid & 63;
  const int lr = lane & 15;
  const int lg = lane >> 4;
  const ushort* base = qkv + (size_t)b * NTOK * 2304 + hh * 64;
  const float SC = 0.03608439182435161f;  // 768^-0.5

  bf16x8 qf[2];
  {
    const int qrow = q0 + wave * 16 + lr;
    if (qrow < NTOK) {
      const ushort* qp = base + (size_t)qrow * 2304 + lg * 8;
      qf[0] = *reinterpret_cast<const bf16x8*>(qp);
      qf[1] = *reinterpret_cast<const bf16x8*>(qp + 32);
    } else {
      qf[0] = (bf16x8){0, 0, 0, 0, 0, 0, 0, 0};
      qf[1] = qf[0];
    }
  }

  float mst[4], lst[4];
  f32x4 oacc[4];
#pragma unroll
  for (int i = 0; i < 4; ++i) {
    mst[i] = -1e30f; lst[i] = 0.f;
    oacc[i] = (f32x4){0.f, 0.f, 0.f, 0.f};
  }

  const int skey = tid >> 2;
  const int sc4 = tid & 3;
  const int gswk = gsw(skey);

  for (int t0 = 0; t0 < NTOK; t0 += 64) {
    __syncthreads();
    {
      const int gk = t0 + skey;
      int4 k0v, k1v, v0v, v1v;
      if (gk < NTOK) {
        const int4* kp = reinterpret_cast<const int4*>(base + (size_t)gk * 2304 + 768 + sc4 * 16);
        k0v = kp[0]; k1v = kp[1];
        const int4* vp = reinterpret_cast<const int4*>(base + (size_t)gk * 2304 + 1536 + sc4 * 16);
        v0v = vp[0]; v1v = vp[1];
      } else {
        int4 z; z.x = z.y = z.z = z.w = 0;
        k0v = k1v = v0v = v1v = z;
      }
      *reinterpret_cast<int4*>(&sK[skey * 64 + (((2 * sc4 + 0) + gswk) & 7) * 8]) = k0v;
      *reinterpret_cast<int4*>(&sK[skey * 64 + (((2 * sc4 + 1) + gswk) & 7) * 8]) = k1v;
      const ushort* vs = reinterpret_cast<const ushort*>(&v0v);
      const ushort* vs2 = reinterpret_cast<const ushort*>(&v1v);
#pragma unroll
      for (int i = 0; i < 8; ++i) {
        const int d0 = sc4 * 16 + i;
        const int pg0 = ((skey >> 3) + gsw(d0)) & 7;
        sVt[d0 * 64 + pg0 * 8 + (skey & 7)] = vs[i];
        const int d1 = sc4 * 16 + 8 + i;
        const int pg1 = ((skey >> 3) + gsw(d1)) & 7;
        sVt[d1 * 64 + pg1 * 8 + (skey & 7)] = vs2[i];
      }
    }
    __syncthreads();

    f32x4 sacc[4];
#pragma unroll
    for (int n = 0; n < 4; ++n) sacc[n] = (f32x4){0.f, 0.f, 0.f, 0.f};
#pragma unroll
    for (int n = 0; n < 4; ++n) {
      const int row = n * 16 + lr;
      const int rot = (lr & 7) + 2 * n;
      const bf16x8 kf0 = *reinterpret_cast<const bf16x8*>(&sK[row * 64 + ((lg + rot) & 7) * 8]);
      const bf16x8 kf1 = *reinterpret_cast<const bf16x8*>(&sK[row * 64 + ((4 + lg + rot) & 7) * 8]);
      sacc[n] = __builtin_amdgcn_mfma_f32_16x16x32_bf16(qf[0], kf0, sacc[n], 0, 0, 0);
      sacc[n] = __builtin_amdgcn_mfma_f32_16x16x32_bf16(qf[1], kf1, sacc[n], 0, 0, 0);
    }

    float s[4][4], pm[4];
#pragma unroll
    for (int reg = 0; reg < 4; ++reg) pm[reg] = -1e30f;
#pragma unroll
    for (int n = 0; n < 4; ++n)
#pragma unroll
      for (int reg = 0; reg < 4; ++reg) {
        float v = sacc[n][reg] * SC;
        if (t0 + n * 16 + lr >= NTOK) v = -1e30f;
        s[n][reg] = v;
        pm[reg] = fmaxf(pm[reg], v);
      }
#pragma unroll
    for (int off = 1; off < 16; off <<= 1)
#pragma unroll
      for (int reg = 0; reg < 4; ++reg) pm[reg] = fmaxf(pm[reg], __shfl_xor(pm[reg], off));

    float al[4], rs[4];
#pragma unroll
    for (int reg = 0; reg < 4; ++reg) {
      const float mn = fmaxf(mst[reg], pm[reg]);
      al[reg] = __expf(mst[reg] - mn);
      mst[reg] = mn;
      rs[reg] = 0.f;
    }
#pragma unroll
    for (int n = 0; n < 4; ++n)
#pragma unroll
      for (int reg = 0; reg < 4; ++reg) {
        s[n][reg] = __expf(s[n][reg] - mst[reg]);
        rs[reg] += s[n][reg];
      }
#pragma unroll
    for (int off = 1; off < 16; off <<= 1)
#pragma unroll
      for (int reg = 0; reg < 4; ++reg) rs[reg] += __shfl_xor(rs[reg], off);
#pragma unroll
    for (int reg = 0; reg < 4; ++reg) {
      lst[reg] = lst[reg] * al[reg] + rs[reg];
#pragma unroll
      for (int n = 0; n < 4; ++n) oacc[n][reg] *= al[reg];
    }

#pragma unroll
    for (int n = 0; n < 4; ++n)
#pragma unroll
      for (int reg = 0; reg < 4; ++reg)
        sP[wave][(lg * 4 + reg) * 72 + n * 16 + lr] = f2bf(s[n][reg]);

    const bf16x8 pf0 = *reinterpret_cast<const bf16x8*>(&sP[wave][lr * 72 + lg * 8]);
    const bf16x8 pf1 = *reinterpret_cast<const bf16x8*>(&sP[wave][lr * 72 + 32 + lg * 8]);
#pragma unroll
    for (int n = 0; n < 4; ++n) {
      const int row = n * 16 + lr;
      const int rot = (lr & 7) + 2 * n;
      const bf16x8 vf0 = *reinterpret_cast<const bf16x8*>(&sVt[row * 64 + ((lg + rot) & 7) * 8]);
      const bf16x8 vf1 = *reinterpret_cast<const bf16x8*>(&sVt[row * 64 + ((4 + lg + rot) & 7) * 8]);
      oacc[n] = __builtin_amdgcn_mfma_f32_16x16x32_bf16(pf0, vf0, oacc[n], 0, 0, 0);
      oacc[n] = __builtin_amdgcn_mfma_f32_16x16x32_bf16(pf1, vf1, oacc[n], 0, 0, 0);
    }
  }

#pragma unroll
  for (int reg = 0; reg < 4; ++reg) {
    const int q = q0 + wave * 16 + lg * 4 + reg;
    if (q >= NTOK) continue;
    const float inv = 1.0f / lst[reg];
    ushort* op = o + (size_t)(b * NTOK + q) * 768 + hh * 64;
#pragma unroll
    for (int n = 0; n < 4; ++n) op[n * 16 + lr] = f2bf(oacc[n][reg] * inv);
  }
}

// ---------------------------------------------------------------------------
// Head: LN(cls rows) @ head_w (768x1000) + head_b -> out (16x1000) f32
// ---------------------------------------------------------------------------
__global__ __launch_bounds__(256) void head_kernel(const float* __restrict__ x,
                                                   const float* __restrict__ lw,
                                                   const float* __restrict__ lb,
                                                   const float* __restrict__ hw,
                                                   const float* __restrict__ hb,
                                                   float* __restrict__ out) {
  __shared__ float srow[768];
  __shared__ float sred[8];
  const int b = blockIdx.x, tid = threadIdx.x;
  const float* xr = x + (size_t)b * NTOK * 768;
  for (int i = tid; i < 768; i += 256) srow[i] = xr[i];
  __syncthreads();
  float part = srow[tid] + srow[tid + 256] + srow[tid + 512];
#pragma unroll
  for (int off = 32; off; off >>= 1) part += __shfl_xor(part, off);
  if ((tid & 63) == 0) sred[tid >> 6] = part;
  __syncthreads();
  const float mu = (sred[0] + sred[1] + sred[2] + sred[3]) * (1.0f / 768.0f);
  const float d0 = srow[tid] - mu, d1 = srow[tid + 256] - mu, d2 = srow[tid + 512] - mu;
  float vp = d0 * d0 + d1 * d1 + d2 * d2;
#pragma unroll
  for (int off = 32; off; off >>= 1) vp += __shfl_xor(vp, off);
  if ((tid & 63) == 0) sred[4 + (tid >> 6)] = vp;
  __syncthreads();
  const float rstd = rsqrtf((sred[4] + sred[5] + sred[6] + sred[7]) * (1.0f / 768.0f) + 1e-5f);
  for (int i = tid; i < 768; i += 256) srow[i] = (srow[i] - mu) * rstd * lw[i] + lb[i];
  __syncthreads();
  const int c = blockIdx.y * 250 + tid;
  if (tid < 250 && c < 1000) {
    float a = 0.f;
#pragma unroll 4
    for (int k = 0; k < 768; ++k) a += srow[k] * hw[(size_t)k * 1000 + c];
    out[b * 1000 + c] = a + hb[c];
  }
}

// ---------------------------------------------------------------------------
extern "C" void kernel_launch(void* const* d_in, const int* in_sizes, int n_in,
                              void* d_out, int out_size, void* d_ws, size_t ws_size,
                              hipStream_t stream) {
  const float* img     = (const float*)d_in[0];
  const float* patch_w = (const float*)d_in[1];
  const float* patch_b = (const float*)d_in[2];
  const float* pos_emb = (const float*)d_in[3];
  const float* cls_tok = (const float*)d_in[4];
  const float* ln1_w   = (const float*)d_in[5];
  const float* ln1_b   = (const float*)d_in[6];
  const float* qkv_w   = (const float*)d_in[7];
  const float* out_w   = (const float*)d_in[8];
  const float* out_b   = (const float*)d_in[9];
  const float* ln2_w   = (const float*)d_in[10];
  const float* ln2_b   = (const float*)d_in[11];
  const float* ff1_w   = (const float*)d_in[12];
  const float* ff1_b   = (const float*)d_in[13];
  const float* ff2_w   = (const float*)d_in[14];
  const float* ff2_b   = (const float*)d_in[15];
  const float* hln_w   = (const float*)d_in[16];
  const float* hln_b   = (const float*)d_in[17];
  const float* head_w  = (const float*)d_in[18];
  const float* head_b  = (const float*)d_in[19];
  float* outp = (float*)d_out;

  char* wsp = (char*)d_ws;
  auto alloc = [&](size_t bytes) {
    char* p = wsp;
    wsp += (bytes + 255) & ~(size_t)255;
    return p;
  };
  float*  x    = (float*) alloc((size_t)9232 * 768 * 4);
  ushort* h    = (ushort*)alloc((size_t)9232 * 768 * 2);
  ushort* qkvb = (ushort*)alloc((size_t)9232 * 2304 * 2);
  ushort* mlp  = (ushort*)alloc((size_t)9232 * 3072 * 2);
  ushort* wq   = (ushort*)alloc((size_t)768 * 2304 * 2);
  ushort* wo   = (ushort*)alloc((size_t)768 * 768 * 2);
  ushort* w1   = (ushort*)alloc((size_t)768 * 3072 * 2);
  ushort* w2   = (ushort*)alloc((size_t)3072 * 768 * 2);
  ushort* apatch = mlp;
  ushort* wpatch = wq;

  // ---- patch embedding ----
  convt_kernel<<<dim3(24, 24), 256, 0, stream>>>(patch_w, wpatch, 768, 768);
  im2col_kernel<<<27648, 256, 0, stream>>>(img, apatch);
  gemmP_kernel<EPI_PATCH><<<72 * 6, 256, 0, stream>>>(
      apatch, wpatch, patch_b, pos_emb, x, 9216, 768, 768, 72);
  clspos_kernel<<<48, 256, 0, stream>>>(cls_tok, pos_emb, x);

  // ---- transformer layers ----
  for (int l = 0; l < 12; ++l) {
    ln_kernel<<<9232, 64, 0, stream>>>(x, ln1_w + l * 768, ln1_b + l * 768, h);
    convt_kernel<<<dim3(24, 72), 256, 0, stream>>>(qkv_w + (size_t)l * 768 * 2304, wq, 768, 2304);
    gemm8_kernel<EPI_BF16><<<37 * 9, 512, 0, stream>>>(
        h, wq, nullptr, qkvb, 9232, 2304, 768, 37);
    attn_kernel<<<dim3(192, 10), 256, 0, stream>>>(qkvb, h);  // o -> h
    convt_kernel<<<dim3(24, 24), 256, 0, stream>>>(out_w + (size_t)l * 768 * 768, wo, 768, 768);
    gemmP_kernel<EPI_RES_F32><<<73 * 6, 256, 0, stream>>>(
        h, wo, out_b + l * 768, x, x, 9232, 768, 768, 73);
    ln_kernel<<<9232, 64, 0, stream>>>(x, ln2_w + l * 768, ln2_b + l * 768, h);
    convt_kernel<<<dim3(24, 96), 256, 0, stream>>>(ff1_w + (size_t)l * 768 * 3072, w1, 768, 3072);
    gemm8_kernel<EPI_GELU_BF16><<<37 * 12, 512, 0, stream>>>(
        h, w1, ff1_b + l * 3072, mlp, 9232, 3072, 768, 37);
    convt_kernel<<<dim3(96, 24), 256, 0, stream>>>(ff2_w + (size_t)l * 3072 * 768, w2, 3072, 768);
    gemmP_kernel<EPI_RES_F32><<<73 * 6, 256, 0, stream>>>(
        mlp, w2, ff2_b + l * 768, x, x, 9232, 768, 3072, 73);
  }

  // ---- classification head ----
  head_kernel<<<dim3(16, 4), 256, 0, stream>>>(x, hln_w, hln_b, head_w, head_b, outp);
}